// Round 1
// baseline (1673.985 us; speedup 1.0000x reference)
//
#include <hip/hip_runtime.h>
#include <hip/hip_bf16.h>
#include <cmath>
#include <cstdint>
#include <cstddef>

// Problem constants (match reference)
#define B_  2
#define S_  2048
#define D_  1024
#define H_  16
#define DK_ 64

// ---------------------------------------------------------------------------
// Kernel 0: pack int32 bool mask [B,1,S,S] into bitmask (1 bit per element).
// mask==true means MASKED (score -> -inf), per reference masked_fill.
// ---------------------------------------------------------------------------
__global__ void pack_mask_kernel(const int* __restrict__ mask,
                                 unsigned* __restrict__ bits, int nwords) {
  int i = blockIdx.x * blockDim.x + threadIdx.x;
  if (i >= nwords) return;
  const int* p = mask + (size_t)i * 32;
  unsigned w = 0;
#pragma unroll
  for (int j = 0; j < 32; ++j) w |= (p[j] != 0 ? (1u << j) : 0u);
  bits[i] = w;
}

// ---------------------------------------------------------------------------
// Tiled fp32 GEMM with bias: C = A[M,K] @ W[K,N] + bias[N]
// MODE 0: scatter output to head-split layout [B,H,S,DK] (row=(b,s), col=(h,dk))
// MODE 1: plain row-major [M,N]
// BM=BN=64, BK=16, 256 threads, 4x4 micro-tile per thread.
// ---------------------------------------------------------------------------
template <int MODE>
__global__ __launch_bounds__(256) void gemm_bias_kernel(
    const float* __restrict__ A, const float* __restrict__ W,
    const float* __restrict__ bias, float* __restrict__ C,
    int M, int N, int K) {
  constexpr int BM = 64, BN = 64, BK = 16;
  __shared__ float As[BK][BM];  // k-major for contiguous row fragments
  __shared__ float Bs[BK][BN];

  const int bm = blockIdx.x * BM;
  const int bn = blockIdx.y * BN;
  const int t  = threadIdx.x;
  const int tx = t & 15;        // 0..15 -> output cols
  const int ty = t >> 4;        // 0..15 -> output rows

  // A-tile loader mapping: each thread loads one float4 along K
  const int arow = t >> 2;            // 0..63
  const int akq  = (t & 3) * 4;       // 0,4,8,12
  // B-tile loader mapping: each thread loads one float4 along N
  const int brow = t >> 4;            // 0..15
  const int bcol = (t & 15) * 4;      // 0..60

  float acc[4][4] = {};

  for (int k0 = 0; k0 < K; k0 += BK) {
    float4 a4 = *reinterpret_cast<const float4*>(
        &A[(size_t)(bm + arow) * K + k0 + akq]);
    float4 b4 = *reinterpret_cast<const float4*>(
        &W[(size_t)(k0 + brow) * N + bn + bcol]);
    __syncthreads();  // protect LDS from previous iteration's readers
    As[akq + 0][arow] = a4.x;
    As[akq + 1][arow] = a4.y;
    As[akq + 2][arow] = a4.z;
    As[akq + 3][arow] = a4.w;
    *reinterpret_cast<float4*>(&Bs[brow][bcol]) = b4;
    __syncthreads();

#pragma unroll
    for (int k = 0; k < BK; ++k) {
      float4 av = *reinterpret_cast<const float4*>(&As[k][ty * 4]);
      float4 bv = *reinterpret_cast<const float4*>(&Bs[k][tx * 4]);
      float ar[4] = {av.x, av.y, av.z, av.w};
      float br[4] = {bv.x, bv.y, bv.z, bv.w};
#pragma unroll
      for (int i = 0; i < 4; ++i)
#pragma unroll
        for (int j = 0; j < 4; ++j)
          acc[i][j] = fmaf(ar[i], br[j], acc[i][j]);
    }
  }

#pragma unroll
  for (int i = 0; i < 4; ++i) {
    const int row = bm + ty * 4 + i;
#pragma unroll
    for (int j = 0; j < 4; ++j) {
      const int col = bn + tx * 4 + j;
      const float v = acc[i][j] + bias[col];
      if (MODE == 0) {
        const int b = row >> 11;          // row / S_
        const int s = row & (S_ - 1);     // row % S_
        const int h = col >> 6;           // col / DK_
        const int dk = col & (DK_ - 1);   // col % DK_
        C[(((size_t)(b * H_ + h)) * S_ + s) * DK_ + dk] = v;
      } else {
        C[(size_t)row * N + col] = v;
      }
    }
  }
}

// ---------------------------------------------------------------------------
// Flash-style attention, fp32.
// Grid: (B*H, S/128). Block: 128 threads (2 waves). Each lane owns one Q row:
// q[64] and o[64] live in VGPRs. K/V staged in LDS as 64-row tiles (uniform
// address -> broadcast reads, conflict-free). Online softmax in 16-wide
// chunks to keep the score array at 16 VGPRs.
// Output written to ctx in [B,S,D] layout for the final GEMM.
// ---------------------------------------------------------------------------
__global__ __launch_bounds__(128) void attn_kernel(
    const float* __restrict__ Qh, const float* __restrict__ Kh,
    const float* __restrict__ Vh, const unsigned* __restrict__ mbits,
    float* __restrict__ ctx) {
  __shared__ float Ks[64][DK_];  // 16 KB
  __shared__ float Vs[64][DK_];  // 16 KB

  const int bh   = blockIdx.x;        // b*H + h
  const int b    = bh >> 4;
  const int h    = bh & 15;
  const int wave = threadIdx.x >> 6;
  const int lane = threadIdx.x & 63;
  const int my_q = blockIdx.y * 128 + wave * 64 + lane;

  // Load my Q row into registers
  const float* qp = &Qh[((size_t)bh * S_ + my_q) * DK_];
  float q[DK_];
#pragma unroll
  for (int d = 0; d < DK_; d += 4) {
    float4 v = *reinterpret_cast<const float4*>(&qp[d]);
    q[d] = v.x; q[d + 1] = v.y; q[d + 2] = v.z; q[d + 3] = v.w;
  }
  float o[DK_];
#pragma unroll
  for (int d = 0; d < DK_; ++d) o[d] = 0.f;
  float m = -INFINITY, l = 0.f;

  const unsigned* mrow = &mbits[((size_t)b * S_ + my_q) * (S_ / 32)];

  for (int k0 = 0; k0 < S_; k0 += 64) {
    __syncthreads();
    {
      const float4* kg =
          reinterpret_cast<const float4*>(&Kh[((size_t)bh * S_ + k0) * DK_]);
      const float4* vg =
          reinterpret_cast<const float4*>(&Vh[((size_t)bh * S_ + k0) * DK_]);
      float4* ks = reinterpret_cast<float4*>(&Ks[0][0]);
      float4* vs = reinterpret_cast<float4*>(&Vs[0][0]);
#pragma unroll
      for (int it = 0; it < 8; ++it) {
        const int i = threadIdx.x + it * 128;  // 1024 float4s per tile
        ks[i] = kg[i];
        vs[i] = vg[i];
      }
    }
    __syncthreads();

    const unsigned mw0 = mrow[(k0 >> 5) + 0];
    const unsigned mw1 = mrow[(k0 >> 5) + 1];

#pragma unroll
    for (int jc = 0; jc < 4; ++jc) {
      float s[16];
#pragma unroll
      for (int jj = 0; jj < 16; ++jj) {
        const int j = jc * 16 + jj;
        float sv = 0.f;
#pragma unroll
        for (int d = 0; d < DK_; d += 4) {
          float4 kv = *reinterpret_cast<const float4*>(&Ks[j][d]);
          sv = fmaf(q[d + 0], kv.x, sv);
          sv = fmaf(q[d + 1], kv.y, sv);
          sv = fmaf(q[d + 2], kv.z, sv);
          sv = fmaf(q[d + 3], kv.w, sv);
        }
        sv *= 0.125f;  // 1/sqrt(64)
        const unsigned w = (j < 32) ? mw0 : mw1;
        if ((w >> (j & 31)) & 1u) sv = -INFINITY;  // mask==true -> -inf
        s[jj] = sv;
      }
      float cmax = s[0];
#pragma unroll
      for (int jj = 1; jj < 16; ++jj) cmax = fmaxf(cmax, s[jj]);
      const float m_new = fmaxf(m, cmax);
      if (m_new == -INFINITY) continue;  // everything masked so far
      if (m_new > m) {
        const float alpha = __expf(m - m_new);  // m==-inf -> 0, correct
        l *= alpha;
#pragma unroll
        for (int d = 0; d < DK_; ++d) o[d] *= alpha;
        m = m_new;
      }
#pragma unroll
      for (int jj = 0; jj < 16; ++jj) {
        const int j = jc * 16 + jj;
        const float p = __expf(s[jj] - m);  // s==-inf -> 0
        l += p;
#pragma unroll
        for (int d = 0; d < DK_; d += 4) {
          float4 vv = *reinterpret_cast<const float4*>(&Vs[j][d]);
          o[d + 0] = fmaf(p, vv.x, o[d + 0]);
          o[d + 1] = fmaf(p, vv.y, o[d + 1]);
          o[d + 2] = fmaf(p, vv.z, o[d + 2]);
          o[d + 3] = fmaf(p, vv.w, o[d + 3]);
        }
      }
    }
  }

  const float inv = (l > 0.f) ? 1.f / l : 0.f;  // fully-masked row -> 0
  float* op = &ctx[((size_t)(b * S_ + my_q)) * D_ + h * DK_];
#pragma unroll
  for (int d = 0; d < DK_; d += 4) {
    float4 v;
    v.x = o[d + 0] * inv;
    v.y = o[d + 1] * inv;
    v.z = o[d + 2] * inv;
    v.w = o[d + 3] * inv;
    *reinterpret_cast<float4*>(&op[d]) = v;
  }
}

// ---------------------------------------------------------------------------
// Launch
// ---------------------------------------------------------------------------
extern "C" void kernel_launch(void* const* d_in, const int* in_sizes, int n_in,
                              void* d_out, int out_size, void* d_ws,
                              size_t ws_size, hipStream_t stream) {
  const float* query = (const float*)d_in[0];
  const float* key   = (const float*)d_in[1];
  const float* value = (const float*)d_in[2];
  const int*   mask  = (const int*)d_in[3];  // bool -> int32 per harness contract
  const float* Wq = (const float*)d_in[4];
  const float* bq = (const float*)d_in[5];
  const float* Wk = (const float*)d_in[6];
  const float* bk = (const float*)d_in[7];
  const float* Wv = (const float*)d_in[8];
  const float* bv = (const float*)d_in[9];
  const float* Wo = (const float*)d_in[10];
  const float* bo = (const float*)d_in[11];
  float* out = (float*)d_out;

  const size_t nElem = (size_t)B_ * S_ * D_;  // 4,194,304
  float* ws = (float*)d_ws;
  float* Qh  = ws;               // [B,H,S,DK]
  float* Kh  = Qh + nElem;
  float* Vh  = Kh + nElem;
  float* ctx = Vh + nElem;       // [B,S,D]
  unsigned* mbits = (unsigned*)(ctx + nElem);  // B*S*S/32 = 262144 words

  const int M = B_ * S_, N = D_, K = D_;

  // 1) pack mask
  {
    const int nwords = B_ * S_ * S_ / 32;
    pack_mask_kernel<<<(nwords + 255) / 256, 256, 0, stream>>>(mask, mbits,
                                                               nwords);
  }
  // 2) QKV projections -> head-split layout
  {
    dim3 grid(M / 64, N / 64);
    gemm_bias_kernel<0><<<grid, 256, 0, stream>>>(query, Wq, bq, Qh, M, N, K);
    gemm_bias_kernel<0><<<grid, 256, 0, stream>>>(key,   Wk, bk, Kh, M, N, K);
    gemm_bias_kernel<0><<<grid, 256, 0, stream>>>(value, Wv, bv, Vh, M, N, K);
  }
  // 3) attention
  {
    dim3 grid(B_ * H_, S_ / 128);
    attn_kernel<<<grid, 128, 0, stream>>>(Qh, Kh, Vh, mbits, ctx);
  }
  // 4) output projection -> d_out
  {
    dim3 grid(M / 64, N / 64);
    gemm_bias_kernel<1><<<grid, 256, 0, stream>>>(ctx, Wo, bo, out, M, N, K);
  }
}

// Round 2
// 486.154 us; speedup vs baseline: 3.4433x; 3.4433x over previous
//
#include <hip/hip_runtime.h>
#include <hip/hip_bf16.h>
#include <cmath>
#include <cstdint>
#include <cstddef>

#define B_  2
#define S_  2048
#define D_  1024
#define H_  16
#define DK_ 64
#define NEG_BIG (-1e30f)

typedef __attribute__((ext_vector_type(8))) short bf16x8;
typedef __attribute__((ext_vector_type(4))) float f32x4;

static __device__ __forceinline__ unsigned short f2bf(float f) {
  __hip_bfloat16 h = __float2bfloat16(f);
  return *reinterpret_cast<unsigned short*>(&h);
}

// ---------------------------------------------------------------------------
// pack int32 bool mask [B,1,S,S] -> bitmask. bit=1 means MASKED (-> -inf).
// ---------------------------------------------------------------------------
__global__ void pack_mask_kernel(const int* __restrict__ mask,
                                 unsigned* __restrict__ bits, int nwords) {
  int i = blockIdx.x * blockDim.x + threadIdx.x;
  if (i >= nwords) return;
  const int* p = mask + (size_t)i * 32;
  unsigned w = 0;
#pragma unroll
  for (int j = 0; j < 32; ++j) w |= (p[j] != 0 ? (1u << j) : 0u);
  bits[i] = w;
}

// ---------------------------------------------------------------------------
// fp32 -> bf16 convert (8 elems/thread)
// ---------------------------------------------------------------------------
__global__ void cvt_f32_bf16_kernel(const float* __restrict__ in,
                                    unsigned short* __restrict__ out, int n8) {
  int i = blockIdx.x * blockDim.x + threadIdx.x;
  if (i >= n8) return;
  const float4* p = reinterpret_cast<const float4*>(in) + (size_t)i * 2;
  float4 a = p[0], b = p[1];
  ushort4 o0 = {f2bf(a.x), f2bf(a.y), f2bf(a.z), f2bf(a.w)};
  ushort4 o1 = {f2bf(b.x), f2bf(b.y), f2bf(b.z), f2bf(b.w)};
  ushort4* q = reinterpret_cast<ushort4*>(out) + (size_t)i * 2;
  q[0] = o0;
  q[1] = o1;
}

// ---------------------------------------------------------------------------
// W [K=1024][N=1024] fp32 -> Wt bf16 [N][K] (transpose + convert)
// ---------------------------------------------------------------------------
__global__ __launch_bounds__(256) void transpose_w_kernel(
    const float* __restrict__ W, unsigned short* __restrict__ Wt) {
  __shared__ unsigned short tile[32][33];
  const int r0 = blockIdx.y * 32, c0 = blockIdx.x * 32;
  const int t = threadIdx.x;
  {
    const int r = t >> 3, c4 = (t & 7) * 4;
    float4 v = *reinterpret_cast<const float4*>(&W[(size_t)(r0 + r) * D_ + c0 + c4]);
    tile[c4 + 0][r] = f2bf(v.x);
    tile[c4 + 1][r] = f2bf(v.y);
    tile[c4 + 2][r] = f2bf(v.z);
    tile[c4 + 3][r] = f2bf(v.w);
  }
  __syncthreads();
  {
    const int n = t >> 3, k4 = (t & 7) * 4;
    ushort4 o = {tile[n][k4 + 0], tile[n][k4 + 1], tile[n][k4 + 2], tile[n][k4 + 3]};
    *reinterpret_cast<ushort4*>(&Wt[(size_t)(c0 + n) * D_ + r0 + k4]) = o;
  }
}

// ---------------------------------------------------------------------------
// bf16 MFMA GEMM: C = A[M=4096,K=1024] @ Wt^T + bias.  Wt is [N][K] bf16.
// 64x64 tile, BK=32, 256 threads (4 waves, 2x2 quadrant of 32x32 each).
// MODE 0: Q -> bf16 [B,H,S,DK], scaled by 0.125
// MODE 1: K -> bf16 [B,H,S,DK]
// MODE 2: V -> bf16 [B,H,DK,S]  (transposed for attention B-operand)
// MODE 3: out fp32 [M][N]
// ---------------------------------------------------------------------------
template <int MODE>
__global__ __launch_bounds__(256) void gemm_bf16_kernel(
    const unsigned short* __restrict__ A, const unsigned short* __restrict__ Wt,
    const float* __restrict__ bias, void* __restrict__ Cout) {
  constexpr int K = D_;
  __shared__ __attribute__((aligned(16))) unsigned short as_[64 * 32];
  __shared__ __attribute__((aligned(16))) unsigned short bs_[64 * 32];
  const int bm = blockIdx.x * 64, bn = blockIdx.y * 64;
  const int t = threadIdx.x, wv = t >> 6, lane = t & 63;
  const int r = lane & 15, g = lane >> 4;
  const int wm = (wv >> 1) * 32, wn = (wv & 1) * 32;
  const int srow = 16 * wv + (lane >> 2);
  const int scol = 8 * (lane & 3);

  f32x4 acc[2][2] = {};

  for (int k0 = 0; k0 < K; k0 += 32) {
    bf16x8 av = *reinterpret_cast<const bf16x8*>(&A[(size_t)(bm + srow) * K + k0 + scol]);
    bf16x8 bv = *reinterpret_cast<const bf16x8*>(&Wt[(size_t)(bn + srow) * K + k0 + scol]);
    __syncthreads();
    *reinterpret_cast<bf16x8*>(&as_[512 * wv + 8 * lane]) = av;
    *reinterpret_cast<bf16x8*>(&bs_[512 * wv + 8 * lane]) = bv;
    __syncthreads();
    bf16x8 a0 = *reinterpret_cast<const bf16x8*>(&as_[(wm + r) * 32 + 8 * g]);
    bf16x8 a1 = *reinterpret_cast<const bf16x8*>(&as_[(wm + 16 + r) * 32 + 8 * g]);
    bf16x8 b0 = *reinterpret_cast<const bf16x8*>(&bs_[(wn + r) * 32 + 8 * g]);
    bf16x8 b1 = *reinterpret_cast<const bf16x8*>(&bs_[(wn + 16 + r) * 32 + 8 * g]);
    acc[0][0] = __builtin_amdgcn_mfma_f32_16x16x32_bf16(a0, b0, acc[0][0], 0, 0, 0);
    acc[0][1] = __builtin_amdgcn_mfma_f32_16x16x32_bf16(a0, b1, acc[0][1], 0, 0, 0);
    acc[1][0] = __builtin_amdgcn_mfma_f32_16x16x32_bf16(a1, b0, acc[1][0], 0, 0, 0);
    acc[1][1] = __builtin_amdgcn_mfma_f32_16x16x32_bf16(a1, b1, acc[1][1], 0, 0, 0);
  }

#pragma unroll
  for (int mf = 0; mf < 2; ++mf)
#pragma unroll
    for (int nf = 0; nf < 2; ++nf)
#pragma unroll
      for (int reg = 0; reg < 4; ++reg) {
        const int row = bm + wm + 16 * mf + 4 * g + reg;
        const int col = bn + wn + 16 * nf + r;
        float v = acc[mf][nf][reg] + bias[col];
        if constexpr (MODE == 3) {
          ((float*)Cout)[(size_t)row * D_ + col] = v;
        } else {
          const int bb = row >> 11, s = row & (S_ - 1);
          const int h = col >> 6, dk = col & (DK_ - 1);
          unsigned short* o = (unsigned short*)Cout;
          if constexpr (MODE == 0)
            o[(((size_t)(bb * H_ + h)) * S_ + s) * DK_ + dk] = f2bf(v * 0.125f);
          else if constexpr (MODE == 1)
            o[(((size_t)(bb * H_ + h)) * S_ + s) * DK_ + dk] = f2bf(v);
          else
            o[(((size_t)(bb * H_ + h)) * DK_ + dk) * S_ + s] = f2bf(v);
        }
      }
}

// ---------------------------------------------------------------------------
// MFMA flash attention. Grid: 1024 blocks x 256 thr (4 waves).
// Wave owns 16 q rows; K-tiles of 64 keys. Q frags in VGPRs; K / V^T frags
// read directly from global (L2-resident per head via XCD swizzle).
// Softmax wave-parallel on S-fragments; P reshaped via per-wave LDS buffer.
// Output: ctx bf16 [B,S,D].
// ---------------------------------------------------------------------------
__global__ __launch_bounds__(256) void attn_mfma_kernel(
    const unsigned short* __restrict__ Qh, const unsigned short* __restrict__ Kh,
    const unsigned short* __restrict__ VT, const unsigned* __restrict__ mbits,
    unsigned short* __restrict__ ctx) {
  __shared__ __attribute__((aligned(16))) unsigned short plds[4][16][72];

  const int flat = blockIdx.x;
  const int xcd = flat & 7, slot = flat >> 3;
  const int bh = xcd * 4 + (slot & 3);  // 4 heads per XCD -> K/V L2-resident
  const int qblk = slot >> 2;
  const int b = bh >> 4, h = bh & 15;
  const int wv = threadIdx.x >> 6, lane = threadIdx.x & 63;
  const int r = lane & 15, g = lane >> 4;
  const int qbase = qblk * 64 + wv * 16;

  // Q A-fragments (row = qbase + r, k = dk), already pre-scaled by 0.125
  const unsigned short* qrow = &Qh[((size_t)bh * S_ + qbase + r) * DK_];
  const bf16x8 qa0 = *(const bf16x8*)&qrow[8 * g];
  const bf16x8 qa1 = *(const bf16x8*)&qrow[32 + 8 * g];

  f32x4 o[4] = {};
  float m_[4] = {NEG_BIG, NEG_BIG, NEG_BIG, NEG_BIG};
  float l_[4] = {};

  const unsigned* mbase = &mbits[((size_t)b * S_ + qbase + 4 * g) * (S_ / 32)];
  const unsigned short* Khead = &Kh[(size_t)bh * S_ * DK_];
  const unsigned short* Vhead = &VT[(size_t)bh * DK_ * S_];

  for (int k0 = 0; k0 < S_; k0 += 64) {
    // ---- QK^T ----
    f32x4 sc[4] = {};
#pragma unroll
    for (int nf = 0; nf < 4; ++nf) {
      const unsigned short* krow = &Khead[(size_t)(k0 + nf * 16 + r) * DK_];
      bf16x8 kb0 = *(const bf16x8*)&krow[8 * g];
      bf16x8 kb1 = *(const bf16x8*)&krow[32 + 8 * g];
      sc[nf] = __builtin_amdgcn_mfma_f32_16x16x32_bf16(qa0, kb0, sc[nf], 0, 0, 0);
      sc[nf] = __builtin_amdgcn_mfma_f32_16x16x32_bf16(qa1, kb1, sc[nf], 0, 0, 0);
    }
    // ---- mask ----
    unsigned w0[4], w1[4];
#pragma unroll
    for (int reg = 0; reg < 4; ++reg) {
      uint2 mw = *reinterpret_cast<const uint2*>(mbase + (size_t)reg * (S_ / 32) + (k0 >> 5));
      w0[reg] = mw.x;
      w1[reg] = mw.y;
    }
#pragma unroll
    for (int nf = 0; nf < 4; ++nf)
#pragma unroll
      for (int reg = 0; reg < 4; ++reg) {
        const unsigned w = (nf < 2) ? w0[reg] : w1[reg];
        const bool bad = (w >> (((nf & 1) << 4) + r)) & 1u;
        sc[nf][reg] = bad ? NEG_BIG : sc[nf][reg];
      }
    // ---- online softmax (per q-row = per reg) ----
#pragma unroll
    for (int reg = 0; reg < 4; ++reg) {
      float t0 = fmaxf(fmaxf(sc[0][reg], sc[1][reg]), fmaxf(sc[2][reg], sc[3][reg]));
      t0 = fmaxf(t0, __shfl_xor(t0, 1));
      t0 = fmaxf(t0, __shfl_xor(t0, 2));
      t0 = fmaxf(t0, __shfl_xor(t0, 4));
      t0 = fmaxf(t0, __shfl_xor(t0, 8));
      const float mn = fmaxf(m_[reg], t0);
      const float alpha = __expf(m_[reg] - mn);  // finite sentinel: no NaN
      m_[reg] = mn;
      float p0 = __expf(sc[0][reg] - mn);
      float p1 = __expf(sc[1][reg] - mn);
      float p2 = __expf(sc[2][reg] - mn);
      float p3 = __expf(sc[3][reg] - mn);
      sc[0][reg] = p0; sc[1][reg] = p1; sc[2][reg] = p2; sc[3][reg] = p3;
      float rs = (p0 + p1) + (p2 + p3);
      rs += __shfl_xor(rs, 1);
      rs += __shfl_xor(rs, 2);
      rs += __shfl_xor(rs, 4);
      rs += __shfl_xor(rs, 8);
      l_[reg] = l_[reg] * alpha + rs;
      o[0][reg] *= alpha;
      o[1][reg] *= alpha;
      o[2][reg] *= alpha;
      o[3][reg] *= alpha;
    }
    // ---- P -> LDS (re-shape C-frag -> A-frag layout) ----
#pragma unroll
    for (int nf = 0; nf < 4; ++nf)
#pragma unroll
      for (int reg = 0; reg < 4; ++reg)
        plds[wv][4 * g + reg][16 * nf + r] = f2bf(sc[nf][reg]);
    const bf16x8 pa0 = *(const bf16x8*)&plds[wv][r][8 * g];
    const bf16x8 pa1 = *(const bf16x8*)&plds[wv][r][32 + 8 * g];
    // ---- PV ----
#pragma unroll
    for (int nf = 0; nf < 4; ++nf) {
      const unsigned short* vrow = &Vhead[(size_t)(nf * 16 + r) * S_ + k0];
      bf16x8 vb0 = *(const bf16x8*)&vrow[8 * g];
      bf16x8 vb1 = *(const bf16x8*)&vrow[32 + 8 * g];
      o[nf] = __builtin_amdgcn_mfma_f32_16x16x32_bf16(pa0, vb0, o[nf], 0, 0, 0);
      o[nf] = __builtin_amdgcn_mfma_f32_16x16x32_bf16(pa1, vb1, o[nf], 0, 0, 0);
    }
  }

  float inv[4];
#pragma unroll
  for (int reg = 0; reg < 4; ++reg)
    inv[reg] = (m_[reg] == NEG_BIG) ? 0.f : 1.f / l_[reg];  // fully-masked -> 0
#pragma unroll
  for (int nf = 0; nf < 4; ++nf)
#pragma unroll
    for (int reg = 0; reg < 4; ++reg) {
      const int q = qbase + 4 * g + reg;
      ctx[((size_t)(b * S_ + q)) * D_ + h * DK_ + 16 * nf + r] = f2bf(o[nf][reg] * inv[reg]);
    }
}

// ---------------------------------------------------------------------------
// Launch
// ---------------------------------------------------------------------------
extern "C" void kernel_launch(void* const* d_in, const int* in_sizes, int n_in,
                              void* d_out, int out_size, void* d_ws,
                              size_t ws_size, hipStream_t stream) {
  const float* query = (const float*)d_in[0];
  const float* key   = (const float*)d_in[1];
  const float* value = (const float*)d_in[2];
  const int*   mask  = (const int*)d_in[3];
  const float* Wq = (const float*)d_in[4];
  const float* bq = (const float*)d_in[5];
  const float* Wk = (const float*)d_in[6];
  const float* bk = (const float*)d_in[7];
  const float* Wv = (const float*)d_in[8];
  const float* bv = (const float*)d_in[9];
  const float* Wo = (const float*)d_in[10];
  const float* bo = (const float*)d_in[11];
  float* out = (float*)d_out;

  const size_t nElem = (size_t)B_ * S_ * D_;  // 4,194,304
  const size_t wElem = (size_t)D_ * D_;       // 1,048,576
  unsigned short* ws = (unsigned short*)d_ws;
  unsigned short* qb   = ws;
  unsigned short* kb   = qb + nElem;
  unsigned short* vb   = kb + nElem;
  unsigned short* wtq  = vb + nElem;
  unsigned short* wtk  = wtq + wElem;
  unsigned short* wtv  = wtk + wElem;
  unsigned short* wto  = wtv + wElem;
  unsigned short* Qh   = wto + wElem;
  unsigned short* Kh   = Qh + nElem;
  unsigned short* VT   = Kh + nElem;
  unsigned short* ctxb = VT + nElem;
  unsigned* mbits = (unsigned*)(ctxb + nElem);

  // 1) pack mask
  {
    const int nwords = B_ * S_ * S_ / 32;
    pack_mask_kernel<<<(nwords + 255) / 256, 256, 0, stream>>>(mask, mbits, nwords);
  }
  // 2) convert activations to bf16
  {
    const int n8 = (int)(nElem / 8);
    const int blocks = (n8 + 255) / 256;
    cvt_f32_bf16_kernel<<<blocks, 256, 0, stream>>>(query, qb, n8);
    cvt_f32_bf16_kernel<<<blocks, 256, 0, stream>>>(key,   kb, n8);
    cvt_f32_bf16_kernel<<<blocks, 256, 0, stream>>>(value, vb, n8);
  }
  // 3) transpose+convert weights
  {
    dim3 grid(32, 32);
    transpose_w_kernel<<<grid, 256, 0, stream>>>(Wq, wtq);
    transpose_w_kernel<<<grid, 256, 0, stream>>>(Wk, wtk);
    transpose_w_kernel<<<grid, 256, 0, stream>>>(Wv, wtv);
    transpose_w_kernel<<<grid, 256, 0, stream>>>(Wo, wto);
  }
  // 4) QKV projections
  {
    dim3 grid(64, 16);  // M/64, N/64
    gemm_bf16_kernel<0><<<grid, 256, 0, stream>>>(qb, wtq, bq, Qh);
    gemm_bf16_kernel<1><<<grid, 256, 0, stream>>>(kb, wtk, bk, Kh);
    gemm_bf16_kernel<2><<<grid, 256, 0, stream>>>(vb, wtv, bv, VT);
  }
  // 5) attention
  attn_mfma_kernel<<<1024, 256, 0, stream>>>(Qh, Kh, VT, mbits, ctxb);
  // 6) output projection
  {
    dim3 grid(64, 16);
    gemm_bf16_kernel<3><<<grid, 256, 0, stream>>>(ctxb, wto, bo, out);
  }
}

// Round 4
// 372.982 us; speedup vs baseline: 4.4881x; 1.3034x over previous
//
#include <hip/hip_runtime.h>
#include <hip/hip_bf16.h>
#include <cmath>
#include <cstdint>
#include <cstddef>

#define B_  2
#define S_  2048
#define D_  1024
#define H_  16
#define DK_ 64
#define NEG_BIG (-1e30f)

typedef __attribute__((ext_vector_type(8))) short bf16x8;
typedef __attribute__((ext_vector_type(4))) float f32x4;
typedef __attribute__((ext_vector_type(16))) float f32x16;

static __device__ __forceinline__ unsigned short f2bf(float f) {
  __hip_bfloat16 h = __float2bfloat16(f);
  return *reinterpret_cast<unsigned short*>(&h);
}

static __device__ __forceinline__ unsigned cvtpk(float lo, float hi) {
  unsigned d;
  asm("v_cvt_pk_bf16_f32 %0, %1, %2" : "=v"(d) : "v"(lo), "v"(hi));
  return d;
}
#define SWAP32(a, b) asm("v_permlane32_swap_b32 %0, %1" : "+v"(a), "+v"(b))

// ---------------------------------------------------------------------------
// pack int32 bool mask [B,1,S,S] -> bitmask. bit=1 means MASKED (-> -inf).
// ---------------------------------------------------------------------------
__global__ void pack_mask_kernel(const int* __restrict__ mask,
                                 unsigned* __restrict__ bits, int nwords) {
  int i = blockIdx.x * blockDim.x + threadIdx.x;
  if (i >= nwords) return;
  const int* p = mask + (size_t)i * 32;
  unsigned w = 0;
#pragma unroll
  for (int j = 0; j < 32; ++j) w |= (p[j] != 0 ? (1u << j) : 0u);
  bits[i] = w;
}

// ---------------------------------------------------------------------------
// fp32 -> bf16 convert (8 elems/thread)
// ---------------------------------------------------------------------------
__global__ void cvt_f32_bf16_kernel(const float* __restrict__ in,
                                    unsigned short* __restrict__ out, int n8) {
  int i = blockIdx.x * blockDim.x + threadIdx.x;
  if (i >= n8) return;
  const float4* p = reinterpret_cast<const float4*>(in) + (size_t)i * 2;
  float4 a = p[0], b = p[1];
  ushort4 o0 = {f2bf(a.x), f2bf(a.y), f2bf(a.z), f2bf(a.w)};
  ushort4 o1 = {f2bf(b.x), f2bf(b.y), f2bf(b.z), f2bf(b.w)};
  ushort4* q = reinterpret_cast<ushort4*>(out) + (size_t)i * 2;
  q[0] = o0;
  q[1] = o1;
}

// ---------------------------------------------------------------------------
// W [K=1024][N=1024] fp32 -> Wt bf16 [N][K] (transpose + convert)
// ---------------------------------------------------------------------------
__global__ __launch_bounds__(256) void transpose_w_kernel(
    const float* __restrict__ W, unsigned short* __restrict__ Wt) {
  __shared__ unsigned short tile[32][33];
  const int r0 = blockIdx.y * 32, c0 = blockIdx.x * 32;
  const int t = threadIdx.x;
  {
    const int r = t >> 3, c4 = (t & 7) * 4;
    float4 v = *reinterpret_cast<const float4*>(&W[(size_t)(r0 + r) * D_ + c0 + c4]);
    tile[c4 + 0][r] = f2bf(v.x);
    tile[c4 + 1][r] = f2bf(v.y);
    tile[c4 + 2][r] = f2bf(v.z);
    tile[c4 + 3][r] = f2bf(v.w);
  }
  __syncthreads();
  {
    const int n = t >> 3, k4 = (t & 7) * 4;
    ushort4 o = {tile[n][k4 + 0], tile[n][k4 + 1], tile[n][k4 + 2], tile[n][k4 + 3]};
    *reinterpret_cast<ushort4*>(&Wt[(size_t)(c0 + n) * D_ + r0 + k4]) = o;
  }
}

// ---------------------------------------------------------------------------
// bf16 MFMA GEMM with global_load_lds staging (m97 2-barrier recipe).
// C = A[M=4096,K=1024] @ Wt^T + bias.  Wt is [N][K] bf16.
// 64x64 tile, BK=32, 256 threads (4 waves, 2x2 quadrant of 32x32 each).
// MODE 0: Q -> bf16 [B,H,S,DK], scaled by 0.125
// MODE 1: K -> bf16 [B,H,S,DK]
// MODE 2: V -> bf16 [B,H,DK,S]  (transposed for attention B-operand)
// MODE 3: out fp32 [M][N]
// ---------------------------------------------------------------------------
template <int MODE>
__global__ __launch_bounds__(256) void gemm_bf16_kernel(
    const unsigned short* __restrict__ A, const unsigned short* __restrict__ Wt,
    const float* __restrict__ bias, void* __restrict__ Cout) {
  constexpr int K = D_;
  __shared__ __attribute__((aligned(16))) unsigned short as_[64 * 32];
  __shared__ __attribute__((aligned(16))) unsigned short bs_[64 * 32];
  const int bm = blockIdx.x * 64, bn = blockIdx.y * 64;
  const int t = threadIdx.x, wv = t >> 6, lane = t & 63;
  const int r = lane & 15, g = lane >> 4;
  const int wm = (wv >> 1) * 32, wn = (wv & 1) * 32;
  // gload mapping: wave wv stages rows 16wv..16wv+15 (row=16wv+lane/4, col 8*(lane%4))
  const int grow = 16 * wv + (lane >> 2);
  const int gcol = (lane & 3) * 8;

  typedef __attribute__((address_space(3))) unsigned int lds_u32;
  typedef __attribute__((address_space(1))) const unsigned int glb_u32;
  lds_u32* asl = (lds_u32*)(as_ + 16 * wv * 32);
  lds_u32* bsl = (lds_u32*)(bs_ + 16 * wv * 32);

  f32x4 acc[2][2] = {};

  for (int k0 = 0; k0 < K; k0 += 32) {
    __syncthreads();  // prev iteration's ds_reads done
    __builtin_amdgcn_global_load_lds(
        (glb_u32*)&A[(size_t)(bm + grow) * K + k0 + gcol], asl, 16, 0, 0);
    __builtin_amdgcn_global_load_lds(
        (glb_u32*)&Wt[(size_t)(bn + grow) * K + k0 + gcol], bsl, 16, 0, 0);
    __syncthreads();  // barrier drains vmcnt -> tiles ready

    bf16x8 a0 = *reinterpret_cast<const bf16x8*>(&as_[(wm + r) * 32 + 8 * g]);
    bf16x8 a1 = *reinterpret_cast<const bf16x8*>(&as_[(wm + 16 + r) * 32 + 8 * g]);
    bf16x8 b0 = *reinterpret_cast<const bf16x8*>(&bs_[(wn + r) * 32 + 8 * g]);
    bf16x8 b1 = *reinterpret_cast<const bf16x8*>(&bs_[(wn + 16 + r) * 32 + 8 * g]);
    acc[0][0] = __builtin_amdgcn_mfma_f32_16x16x32_bf16(a0, b0, acc[0][0], 0, 0, 0);
    acc[0][1] = __builtin_amdgcn_mfma_f32_16x16x32_bf16(a0, b1, acc[0][1], 0, 0, 0);
    acc[1][0] = __builtin_amdgcn_mfma_f32_16x16x32_bf16(a1, b0, acc[1][0], 0, 0, 0);
    acc[1][1] = __builtin_amdgcn_mfma_f32_16x16x32_bf16(a1, b1, acc[1][1], 0, 0, 0);
  }

#pragma unroll
  for (int mf = 0; mf < 2; ++mf)
#pragma unroll
    for (int nf = 0; nf < 2; ++nf)
#pragma unroll
      for (int reg = 0; reg < 4; ++reg) {
        const int row = bm + wm + 16 * mf + 4 * g + reg;
        const int col = bn + wn + 16 * nf + r;
        float v = acc[mf][nf][reg] + bias[col];
        if constexpr (MODE == 3) {
          ((float*)Cout)[(size_t)row * D_ + col] = v;
        } else {
          const int bb = row >> 11, s = row & (S_ - 1);
          const int h = col >> 6, dk = col & (DK_ - 1);
          unsigned short* o = (unsigned short*)Cout;
          if constexpr (MODE == 0)
            o[(((size_t)(bb * H_ + h)) * S_ + s) * DK_ + dk] = f2bf(v * 0.125f);
          else if constexpr (MODE == 1)
            o[(((size_t)(bb * H_ + h)) * S_ + s) * DK_ + dk] = f2bf(v);
          else
            o[(((size_t)(bb * H_ + h)) * DK_ + dk) * S_ + s] = f2bf(v);
        }
      }
}

// ---------------------------------------------------------------------------
// MFMA flash attention, 32x32x16 swapped-QK^T (T12) + split-K(2) + defer-max.
// Grid 1024 blocks x 256 thr (4 waves). Wave = (qsub, khalf):
//   qsub selects 32 q-rows, khalf selects 1024-key half. Lane: q = lane&31,
//   hi = lane>>5. S^T = mfma(A=K, B=Q): lane holds P[q][crow(reg,hi)] for its
//   q -> softmax is 15 in-lane fmax + 1 shfl_xor(32). P repacked to A-frags
//   via 8 cvt_pk + 4 permlane32_swap (no LDS). K prefetched 1 tile ahead.
//   Split-K halves merged via LDS epilogue. Output ctx bf16 [B,S,D].
// ---------------------------------------------------------------------------
__global__ __launch_bounds__(256) void attn_mfma_kernel(
    const unsigned short* __restrict__ Qh, const unsigned short* __restrict__ Kh,
    const unsigned short* __restrict__ VT, const unsigned* __restrict__ mbits,
    unsigned short* __restrict__ ctx) {
  __shared__ float mlds[2][2][32];
  __shared__ float llds[2][2][32];
  __shared__ float olds[2][2][16][64];  // [qsub][dkblk][reg][lane]

  const int flat = blockIdx.x;
  const int bh = (flat & 7) * 4 + ((flat >> 3) & 3);  // 4 heads per XCD
  const int qblk = flat >> 5;
  const int b = bh >> 4, h = bh & 15;
  const int wv = threadIdx.x >> 6, lane = threadIdx.x & 63;
  const int qsub = wv & 1, khalf = wv >> 1;
  const int ql = lane & 31, hi = lane >> 5;
  const int qrow = qblk * 64 + qsub * 32 + ql;

  // Q B-frags (col=q=lane&31, k=dk), pre-scaled by 0.125 in projection
  const unsigned short* Qrow = &Qh[((size_t)bh * S_ + qrow) * DK_];
  bf16x8 qf[4];
#pragma unroll
  for (int i = 0; i < 4; ++i)
    qf[i] = *(const bf16x8*)&Qrow[16 * i + 8 * hi];

  const unsigned short* Khead = &Kh[(size_t)bh * S_ * DK_];
  const unsigned short* Vhead = &VT[(size_t)bh * DK_ * S_];
  const unsigned* mrow = &mbits[((size_t)b * S_ + qrow) * (S_ / 32)];

  f32x16 o0 = {}, o1 = {};
  float m = NEG_BIG, l = 0.f;

  const int tbeg = khalf * 32, tend = tbeg + 32;  // tiles of 32 keys
  bf16x8 kf[4];
#pragma unroll
  for (int i = 0; i < 4; ++i)
    kf[i] = *(const bf16x8*)&Khead[(size_t)(tbeg * 32 + ql) * DK_ + 16 * i + 8 * hi];
  unsigned mw = mrow[tbeg];

  for (int tt = tbeg; tt < tend; ++tt) {
    // ---- S^T = K · Q^T  (C: col=lane&31=q, row=crow(reg,hi)=key) ----
    f32x16 sc = {};
#pragma unroll
    for (int i = 0; i < 4; ++i)
      sc = __builtin_amdgcn_mfma_f32_32x32x16_bf16(kf[i], qf[i], sc, 0, 0, 0);

    // ---- prefetch next K tile + mask word ----
    const int tn = (tt + 1 < tend) ? tt + 1 : tt;
    bf16x8 kn[4];
#pragma unroll
    for (int i = 0; i < 4; ++i)
      kn[i] = *(const bf16x8*)&Khead[(size_t)(tn * 32 + ql) * DK_ + 16 * i + 8 * hi];
    const unsigned mwn = mrow[tn];

    // ---- V B-frags for this tile (col=dk, k=key) ----
    bf16x8 vf[2][2];  // [k-half kk][dkblk]
#pragma unroll
    for (int kk = 0; kk < 2; ++kk)
#pragma unroll
      for (int db = 0; db < 2; ++db)
        vf[kk][db] = *(const bf16x8*)
            &Vhead[(size_t)(db * 32 + ql) * S_ + tt * 32 + kk * 16 + 8 * hi];

    // ---- mask (bit crow(reg,hi) of this q-row's word) ----
    const unsigned msh = mw >> (4 * hi);
#pragma unroll
    for (int reg = 0; reg < 16; ++reg) {
      const int creg = (reg & 3) + 8 * (reg >> 2);
      if ((msh >> creg) & 1u) sc[reg] = NEG_BIG;
    }

    // ---- row max: in-lane over 16 regs, then cross-hi ----
    float px = sc[0];
#pragma unroll
    for (int reg = 1; reg < 16; ++reg) px = fmaxf(px, sc[reg]);
    px = fmaxf(px, __shfl_xor(px, 32));

    // ---- defer-max rescale (T13, THR=8) ----
    if (!__all(px - m <= 8.f)) {
      const float mn = fmaxf(m, px);
      const float alpha = __expf(m - mn);  // exp(-inf-ish)=0 wipes masked-prefix garbage
      m = mn;
      l *= alpha;
#pragma unroll
      for (int reg = 0; reg < 16; ++reg) { o0[reg] *= alpha; o1[reg] *= alpha; }
    }

    // ---- p = exp(s - m), row sum ----
    float rs = 0.f;
#pragma unroll
    for (int reg = 0; reg < 16; ++reg) {
      sc[reg] = __expf(sc[reg] - m);
      rs += sc[reg];
    }
    rs += __shfl_xor(rs, 32);
    l += rs;

    // ---- pack P -> A-frags: 8 cvt_pk + 4 permlane32_swap (T12) ----
    unsigned w0 = cvtpk(sc[0], sc[1]),   w2p = cvtpk(sc[4], sc[5]);
    unsigned w1 = cvtpk(sc[2], sc[3]),   w3p = cvtpk(sc[6], sc[7]);
    unsigned u0 = cvtpk(sc[8], sc[9]),   u2p = cvtpk(sc[12], sc[13]);
    unsigned u1 = cvtpk(sc[10], sc[11]), u3p = cvtpk(sc[14], sc[15]);
    SWAP32(w0, w2p);
    SWAP32(w1, w3p);
    SWAP32(u0, u2p);
    SWAP32(u1, u3p);
    union { unsigned u[4]; bf16x8 v; } pu0, pu1;
    pu0.u[0] = w0; pu0.u[1] = w1; pu0.u[2] = w2p; pu0.u[3] = w3p;
    pu1.u[0] = u0; pu1.u[1] = u1; pu1.u[2] = u2p; pu1.u[3] = u3p;

    // ---- PV: O[q][dk] += P·V ----
    o0 = __builtin_amdgcn_mfma_f32_32x32x16_bf16(pu0.v, vf[0][0], o0, 0, 0, 0);
    o0 = __builtin_amdgcn_mfma_f32_32x32x16_bf16(pu1.v, vf[1][0], o0, 0, 0, 0);
    o1 = __builtin_amdgcn_mfma_f32_32x32x16_bf16(pu0.v, vf[0][1], o1, 0, 0, 0);
    o1 = __builtin_amdgcn_mfma_f32_32x32x16_bf16(pu1.v, vf[1][1], o1, 0, 0, 0);

#pragma unroll
    for (int i = 0; i < 4; ++i) kf[i] = kn[i];
    mw = mwn;
  }

  // ---- split-K merge epilogue ----
  if (lane < 32) {
    mlds[khalf][qsub][ql] = m;
    llds[khalf][qsub][ql] = l;
  }
  if (khalf == 0) {
#pragma unroll
    for (int reg = 0; reg < 16; ++reg) {
      olds[qsub][0][reg][lane] = o0[reg];
      olds[qsub][1][reg][lane] = o1[reg];
    }
  }
  __syncthreads();
  if (khalf == 1) {
#pragma unroll
    for (int reg = 0; reg < 16; ++reg) {
      const int crow = (reg & 3) + 8 * (reg >> 2) + 4 * hi;
      const float m0 = mlds[0][qsub][crow], l0 = llds[0][qsub][crow];
      const float m1 = mlds[1][qsub][crow], l1 = llds[1][qsub][crow];
      const float ms = fmaxf(m0, m1);
      const float f0 = __expf(m0 - ms), f1 = __expf(m1 - ms);
      const float ls = l0 * f0 + l1 * f1;
      const float inv = (ms == NEG_BIG) ? 0.f : 1.f / ls;  // fully-masked row -> 0
      const float v0 = (olds[qsub][0][reg][lane] * f0 + o0[reg] * f1) * inv;
      const float v1 = (olds[qsub][1][reg][lane] * f0 + o1[reg] * f1) * inv;
      const int q = qblk * 64 + qsub * 32 + crow;
      unsigned short* cp = &ctx[((size_t)(b * S_ + q)) * D_ + h * DK_];
      cp[ql] = f2bf(v0);
      cp[32 + ql] = f2bf(v1);
    }
  }
}

// ---------------------------------------------------------------------------
// Launch
// ---------------------------------------------------------------------------
extern "C" void kernel_launch(void* const* d_in, const int* in_sizes, int n_in,
                              void* d_out, int out_size, void* d_ws,
                              size_t ws_size, hipStream_t stream) {
  const float* query = (const float*)d_in[0];
  const float* key   = (const float*)d_in[1];
  const float* value = (const float*)d_in[2];
  const int*   mask  = (const int*)d_in[3];
  const float* Wq = (const float*)d_in[4];
  const float* bq = (const float*)d_in[5];
  const float* Wk = (const float*)d_in[6];
  const float* bk = (const float*)d_in[7];
  const float* Wv = (const float*)d_in[8];
  const float* bv = (const float*)d_in[9];
  const float* Wo = (const float*)d_in[10];
  const float* bo = (const float*)d_in[11];
  float* out = (float*)d_out;

  const size_t nElem = (size_t)B_ * S_ * D_;  // 4,194,304
  const size_t wElem = (size_t)D_ * D_;       // 1,048,576
  unsigned short* ws = (unsigned short*)d_ws;
  unsigned short* qb   = ws;
  unsigned short* kb   = qb + nElem;
  unsigned short* vb   = kb + nElem;
  unsigned short* wtq  = vb + nElem;
  unsigned short* wtk  = wtq + wElem;
  unsigned short* wtv  = wtk + wElem;
  unsigned short* wto  = wtv + wElem;
  unsigned short* Qh   = wto + wElem;
  unsigned short* Kh   = Qh + nElem;
  unsigned short* VT   = Kh + nElem;
  unsigned short* ctxb = VT + nElem;
  unsigned* mbits = (unsigned*)(ctxb + nElem);

  // 1) pack mask
  {
    const int nwords = B_ * S_ * S_ / 32;
    pack_mask_kernel<<<(nwords + 255) / 256, 256, 0, stream>>>(mask, mbits, nwords);
  }
  // 2) convert activations to bf16
  {
    const int n8 = (int)(nElem / 8);
    const int blocks = (n8 + 255) / 256;
    cvt_f32_bf16_kernel<<<blocks, 256, 0, stream>>>(query, qb, n8);
    cvt_f32_bf16_kernel<<<blocks, 256, 0, stream>>>(key,   kb, n8);
    cvt_f32_bf16_kernel<<<blocks, 256, 0, stream>>>(value, vb, n8);
  }
  // 3) transpose+convert weights
  {
    dim3 grid(32, 32);
    transpose_w_kernel<<<grid, 256, 0, stream>>>(Wq, wtq);
    transpose_w_kernel<<<grid, 256, 0, stream>>>(Wk, wtk);
    transpose_w_kernel<<<grid, 256, 0, stream>>>(Wv, wtv);
    transpose_w_kernel<<<grid, 256, 0, stream>>>(Wo, wto);
  }
  // 4) QKV projections
  {
    dim3 grid(64, 16);  // M/64, N/64
    gemm_bf16_kernel<0><<<grid, 256, 0, stream>>>(qb, wtq, bq, Qh);
    gemm_bf16_kernel<1><<<grid, 256, 0, stream>>>(kb, wtk, bk, Kh);
    gemm_bf16_kernel<2><<<grid, 256, 0, stream>>>(vb, wtv, bv, VT);
  }
  // 5) attention
  attn_mfma_kernel<<<1024, 256, 0, stream>>>(Qh, Kh, VT, mbits, ctxb);
  // 6) output projection
  {
    dim3 grid(64, 16);
    gemm_bf16_kernel<3><<<grid, 256, 0, stream>>>(ctxb, wto, bo, out);
  }
}

// Round 5
// 360.446 us; speedup vs baseline: 4.6442x; 1.0348x over previous
//
#include <hip/hip_runtime.h>
#include <hip/hip_bf16.h>
#include <cmath>
#include <cstdint>
#include <cstddef>

#define B_  2
#define S_  2048
#define D_  1024
#define H_  16
#define DK_ 64
#define NEG_BIG (-1e30f)

typedef __attribute__((ext_vector_type(8))) short bf16x8;
typedef __attribute__((ext_vector_type(4))) float f32x4;
typedef __attribute__((ext_vector_type(16))) float f32x16;

static __device__ __forceinline__ unsigned short f2bf(float f) {
  __hip_bfloat16 h = __float2bfloat16(f);
  return *reinterpret_cast<unsigned short*>(&h);
}

static __device__ __forceinline__ unsigned cvtpk(float lo, float hi) {
  unsigned d;
  asm("v_cvt_pk_bf16_f32 %0, %1, %2" : "=v"(d) : "v"(lo), "v"(hi));
  return d;
}
#define SWAP32(a, b) asm("v_permlane32_swap_b32 %0, %1" : "+v"(a), "+v"(b))

// ---------------------------------------------------------------------------
// pack int32 bool mask [B,1,S,S] -> bitmask. bit=1 means MASKED (-> -inf).
// ---------------------------------------------------------------------------
__global__ void pack_mask_kernel(const int* __restrict__ mask,
                                 unsigned* __restrict__ bits, int nwords) {
  int i = blockIdx.x * blockDim.x + threadIdx.x;
  if (i >= nwords) return;
  const int* p = mask + (size_t)i * 32;
  unsigned w = 0;
#pragma unroll
  for (int j = 0; j < 32; ++j) w |= (p[j] != 0 ? (1u << j) : 0u);
  bits[i] = w;
}

// ---------------------------------------------------------------------------
// fp32 -> bf16 convert, fused over q/k/v via blockIdx.y (8 elems/thread)
// ---------------------------------------------------------------------------
__global__ void cvt_f32_bf16_kernel(const float* __restrict__ q,
                                    const float* __restrict__ k,
                                    const float* __restrict__ v,
                                    unsigned short* __restrict__ qo,
                                    unsigned short* __restrict__ ko,
                                    unsigned short* __restrict__ vo, int n8) {
  int i = blockIdx.x * blockDim.x + threadIdx.x;
  if (i >= n8) return;
  const float* in = (blockIdx.y == 0) ? q : (blockIdx.y == 1) ? k : v;
  unsigned short* out = (blockIdx.y == 0) ? qo : (blockIdx.y == 1) ? ko : vo;
  const float4* p = reinterpret_cast<const float4*>(in) + (size_t)i * 2;
  float4 a = p[0], b = p[1];
  ushort4 o0 = {f2bf(a.x), f2bf(a.y), f2bf(a.z), f2bf(a.w)};
  ushort4 o1 = {f2bf(b.x), f2bf(b.y), f2bf(b.z), f2bf(b.w)};
  ushort4* o = reinterpret_cast<ushort4*>(out) + (size_t)i * 2;
  o[0] = o0;
  o[1] = o1;
}

// ---------------------------------------------------------------------------
// W [K=1024][N=1024] fp32 -> Wt bf16 [N][K], fused over 4 weights (blockIdx.z)
// ---------------------------------------------------------------------------
__global__ __launch_bounds__(256) void transpose_w_kernel(
    const float* __restrict__ w0, const float* __restrict__ w1,
    const float* __restrict__ w2, const float* __restrict__ w3,
    unsigned short* __restrict__ t0, unsigned short* __restrict__ t1,
    unsigned short* __restrict__ t2, unsigned short* __restrict__ t3) {
  __shared__ unsigned short tile[32][33];
  const int z = blockIdx.z;
  const float* W = (z == 0) ? w0 : (z == 1) ? w1 : (z == 2) ? w2 : w3;
  unsigned short* Wt = (z == 0) ? t0 : (z == 1) ? t1 : (z == 2) ? t2 : t3;
  const int r0 = blockIdx.y * 32, c0 = blockIdx.x * 32;
  const int t = threadIdx.x;
  {
    const int r = t >> 3, c4 = (t & 7) * 4;
    float4 v = *reinterpret_cast<const float4*>(&W[(size_t)(r0 + r) * D_ + c0 + c4]);
    tile[c4 + 0][r] = f2bf(v.x);
    tile[c4 + 1][r] = f2bf(v.y);
    tile[c4 + 2][r] = f2bf(v.z);
    tile[c4 + 3][r] = f2bf(v.w);
  }
  __syncthreads();
  {
    const int n = t >> 3, k4 = (t & 7) * 4;
    ushort4 o = {tile[n][k4 + 0], tile[n][k4 + 1], tile[n][k4 + 2], tile[n][k4 + 3]};
    *reinterpret_cast<ushort4*>(&Wt[(size_t)(c0 + n) * D_ + r0 + k4]) = o;
  }
}

// ---------------------------------------------------------------------------
// bf16 MFMA GEMM body (64x64 tile, BK=32, 4 waves, global_load_lds staging).
// Returns acc[2][2] f32x4 per thread. Shared by qkv- and out-projection.
// ---------------------------------------------------------------------------
typedef __attribute__((address_space(3))) unsigned int lds_u32;
typedef __attribute__((address_space(1))) const unsigned int glb_u32;

// ---------------------------------------------------------------------------
// Fused QKV projections: blockIdx.z selects {q,k,v}.
// z=0: Q -> bf16 [B,H,S,DK] scaled 0.125; z=1: K -> [B,H,S,DK];
// z=2: V -> [B,H,DK,S] transposed.
// ---------------------------------------------------------------------------
__global__ __launch_bounds__(256) void qkv_gemm_kernel(
    const unsigned short* __restrict__ qb, const unsigned short* __restrict__ kb,
    const unsigned short* __restrict__ vb, const unsigned short* __restrict__ wtq,
    const unsigned short* __restrict__ wtk, const unsigned short* __restrict__ wtv,
    const float* __restrict__ bq, const float* __restrict__ bk,
    const float* __restrict__ bv, unsigned short* __restrict__ Qh,
    unsigned short* __restrict__ Kh, unsigned short* __restrict__ VT) {
  constexpr int K = D_;
  __shared__ __attribute__((aligned(16))) unsigned short as_[64 * 32];
  __shared__ __attribute__((aligned(16))) unsigned short bs_[64 * 32];
  const int z = blockIdx.z;
  const unsigned short* A = (z == 0) ? qb : (z == 1) ? kb : vb;
  const unsigned short* Wt = (z == 0) ? wtq : (z == 1) ? wtk : wtv;
  const float* bias = (z == 0) ? bq : (z == 1) ? bk : bv;

  const int bm = blockIdx.x * 64, bn = blockIdx.y * 64;
  const int t = threadIdx.x, wv = t >> 6, lane = t & 63;
  const int r = lane & 15, g = lane >> 4;
  const int wm = (wv >> 1) * 32, wn = (wv & 1) * 32;
  const int grow = 16 * wv + (lane >> 2);
  const int gcol = (lane & 3) * 8;

  lds_u32* asl = (lds_u32*)(as_ + 16 * wv * 32);
  lds_u32* bsl = (lds_u32*)(bs_ + 16 * wv * 32);

  f32x4 acc[2][2] = {};

  for (int k0 = 0; k0 < K; k0 += 32) {
    __syncthreads();
    __builtin_amdgcn_global_load_lds(
        (glb_u32*)&A[(size_t)(bm + grow) * K + k0 + gcol], asl, 16, 0, 0);
    __builtin_amdgcn_global_load_lds(
        (glb_u32*)&Wt[(size_t)(bn + grow) * K + k0 + gcol], bsl, 16, 0, 0);
    __syncthreads();

    bf16x8 a0 = *reinterpret_cast<const bf16x8*>(&as_[(wm + r) * 32 + 8 * g]);
    bf16x8 a1 = *reinterpret_cast<const bf16x8*>(&as_[(wm + 16 + r) * 32 + 8 * g]);
    bf16x8 b0 = *reinterpret_cast<const bf16x8*>(&bs_[(wn + r) * 32 + 8 * g]);
    bf16x8 b1 = *reinterpret_cast<const bf16x8*>(&bs_[(wn + 16 + r) * 32 + 8 * g]);
    acc[0][0] = __builtin_amdgcn_mfma_f32_16x16x32_bf16(a0, b0, acc[0][0], 0, 0, 0);
    acc[0][1] = __builtin_amdgcn_mfma_f32_16x16x32_bf16(a0, b1, acc[0][1], 0, 0, 0);
    acc[1][0] = __builtin_amdgcn_mfma_f32_16x16x32_bf16(a1, b0, acc[1][0], 0, 0, 0);
    acc[1][1] = __builtin_amdgcn_mfma_f32_16x16x32_bf16(a1, b1, acc[1][1], 0, 0, 0);
  }

#pragma unroll
  for (int mf = 0; mf < 2; ++mf)
#pragma unroll
    for (int nf = 0; nf < 2; ++nf)
#pragma unroll
      for (int reg = 0; reg < 4; ++reg) {
        const int row = bm + wm + 16 * mf + 4 * g + reg;
        const int col = bn + wn + 16 * nf + r;
        const float v = acc[mf][nf][reg] + bias[col];
        const int bb = row >> 11, s = row & (S_ - 1);
        const int h = col >> 6, dk = col & (DK_ - 1);
        if (z == 0)
          Qh[(((size_t)(bb * H_ + h)) * S_ + s) * DK_ + dk] = f2bf(v * 0.125f);
        else if (z == 1)
          Kh[(((size_t)(bb * H_ + h)) * S_ + s) * DK_ + dk] = f2bf(v);
        else
          VT[(((size_t)(bb * H_ + h)) * DK_ + dk) * S_ + s] = f2bf(v);
      }
}

// ---------------------------------------------------------------------------
// Output projection: ctx bf16 [B,S,D] @ Wo^T + bo -> fp32 out.
// ---------------------------------------------------------------------------
__global__ __launch_bounds__(256) void out_gemm_kernel(
    const unsigned short* __restrict__ A, const unsigned short* __restrict__ Wt,
    const float* __restrict__ bias, float* __restrict__ Cout) {
  constexpr int K = D_;
  __shared__ __attribute__((aligned(16))) unsigned short as_[64 * 32];
  __shared__ __attribute__((aligned(16))) unsigned short bs_[64 * 32];
  const int bm = blockIdx.x * 64, bn = blockIdx.y * 64;
  const int t = threadIdx.x, wv = t >> 6, lane = t & 63;
  const int r = lane & 15, g = lane >> 4;
  const int wm = (wv >> 1) * 32, wn = (wv & 1) * 32;
  const int grow = 16 * wv + (lane >> 2);
  const int gcol = (lane & 3) * 8;

  lds_u32* asl = (lds_u32*)(as_ + 16 * wv * 32);
  lds_u32* bsl = (lds_u32*)(bs_ + 16 * wv * 32);

  f32x4 acc[2][2] = {};

  for (int k0 = 0; k0 < K; k0 += 32) {
    __syncthreads();
    __builtin_amdgcn_global_load_lds(
        (glb_u32*)&A[(size_t)(bm + grow) * K + k0 + gcol], asl, 16, 0, 0);
    __builtin_amdgcn_global_load_lds(
        (glb_u32*)&Wt[(size_t)(bn + grow) * K + k0 + gcol], bsl, 16, 0, 0);
    __syncthreads();

    bf16x8 a0 = *reinterpret_cast<const bf16x8*>(&as_[(wm + r) * 32 + 8 * g]);
    bf16x8 a1 = *reinterpret_cast<const bf16x8*>(&as_[(wm + 16 + r) * 32 + 8 * g]);
    bf16x8 b0 = *reinterpret_cast<const bf16x8*>(&bs_[(wn + r) * 32 + 8 * g]);
    bf16x8 b1 = *reinterpret_cast<const bf16x8*>(&bs_[(wn + 16 + r) * 32 + 8 * g]);
    acc[0][0] = __builtin_amdgcn_mfma_f32_16x16x32_bf16(a0, b0, acc[0][0], 0, 0, 0);
    acc[0][1] = __builtin_amdgcn_mfma_f32_16x16x32_bf16(a0, b1, acc[0][1], 0, 0, 0);
    acc[1][0] = __builtin_amdgcn_mfma_f32_16x16x32_bf16(a1, b0, acc[1][0], 0, 0, 0);
    acc[1][1] = __builtin_amdgcn_mfma_f32_16x16x32_bf16(a1, b1, acc[1][1], 0, 0, 0);
  }

#pragma unroll
  for (int mf = 0; mf < 2; ++mf)
#pragma unroll
    for (int nf = 0; nf < 2; ++nf)
#pragma unroll
      for (int reg = 0; reg < 4; ++reg) {
        const int row = bm + wm + 16 * mf + 4 * g + reg;
        const int col = bn + wn + 16 * nf + r;
        Cout[(size_t)row * D_ + col] = acc[mf][nf][reg] + bias[col];
      }
}

// ---------------------------------------------------------------------------
// MFMA flash attention, 32x32x16 swapped-QK^T + split-K(4) + defer-max + T12.
// Grid 2048 blocks x 256 thr (4 waves). Block owns 32 q-rows; wave kh covers
// key-quarter [kh*512, kh*512+512). Lane: q = lane&31. 4-way LDS merge.
// ---------------------------------------------------------------------------
__global__ __launch_bounds__(256) void attn_mfma_kernel(
    const unsigned short* __restrict__ Qh, const unsigned short* __restrict__ Kh,
    const unsigned short* __restrict__ VT, const unsigned* __restrict__ mbits,
    unsigned short* __restrict__ ctx) {
  __shared__ float mlds[4][32];
  __shared__ float llds[4][32];
  __shared__ float olds[3][2][16][64];  // partials from waves 0..2

  const int flat = blockIdx.x;
  const int bh = (flat & 7) * 4 + ((flat >> 3) & 3);  // 4 heads per XCD
  const int qblk = flat >> 5;                          // 0..63
  const int b = bh >> 4, h = bh & 15;
  const int kh = threadIdx.x >> 6, lane = threadIdx.x & 63;
  const int ql = lane & 31, hi = lane >> 5;
  const int qrow = qblk * 32 + ql;

  // Q B-frags (col=q=lane&31, k=dk), pre-scaled by 0.125 in projection
  const unsigned short* Qrow = &Qh[((size_t)bh * S_ + qrow) * DK_];
  bf16x8 qf[4];
#pragma unroll
  for (int i = 0; i < 4; ++i)
    qf[i] = *(const bf16x8*)&Qrow[16 * i + 8 * hi];

  const unsigned short* Khead = &Kh[(size_t)bh * S_ * DK_];
  const unsigned short* Vhead = &VT[(size_t)bh * DK_ * S_];
  const unsigned* mrow = &mbits[((size_t)b * S_ + qrow) * (S_ / 32)];

  f32x16 o0 = {}, o1 = {};
  float m = NEG_BIG, l = 0.f;

  const int tbeg = kh * 16, tend = tbeg + 16;  // 16 tiles of 32 keys
  bf16x8 kf[4];
#pragma unroll
  for (int i = 0; i < 4; ++i)
    kf[i] = *(const bf16x8*)&Khead[(size_t)(tbeg * 32 + ql) * DK_ + 16 * i + 8 * hi];
  unsigned mw = mrow[tbeg];

  for (int tt = tbeg; tt < tend; ++tt) {
    // ---- S^T = K · Q^T  (C: col=lane&31=q, row=crow(reg,hi)=key) ----
    f32x16 sc = {};
    __builtin_amdgcn_s_setprio(1);
#pragma unroll
    for (int i = 0; i < 4; ++i)
      sc = __builtin_amdgcn_mfma_f32_32x32x16_bf16(kf[i], qf[i], sc, 0, 0, 0);
    __builtin_amdgcn_s_setprio(0);

    // ---- prefetch next K tile + mask word ----
    const int tn = (tt + 1 < tend) ? tt + 1 : tt;
    bf16x8 kn[4];
#pragma unroll
    for (int i = 0; i < 4; ++i)
      kn[i] = *(const bf16x8*)&Khead[(size_t)(tn * 32 + ql) * DK_ + 16 * i + 8 * hi];
    const unsigned mwn = mrow[tn];

    // ---- V B-frags for this tile (col=dk, k=key) ----
    bf16x8 vf[2][2];  // [k-half kk][dkblk]
#pragma unroll
    for (int kk = 0; kk < 2; ++kk)
#pragma unroll
      for (int db = 0; db < 2; ++db)
        vf[kk][db] = *(const bf16x8*)
            &Vhead[(size_t)(db * 32 + ql) * S_ + tt * 32 + kk * 16 + 8 * hi];

    // ---- mask (bit crow(reg,hi) of this q-row's word) ----
    const unsigned msh = mw >> (4 * hi);
#pragma unroll
    for (int reg = 0; reg < 16; ++reg) {
      const int creg = (reg & 3) + 8 * (reg >> 2);
      if ((msh >> creg) & 1u) sc[reg] = NEG_BIG;
    }

    // ---- row max: in-lane over 16 regs, then cross-hi ----
    float px = sc[0];
#pragma unroll
    for (int reg = 1; reg < 16; ++reg) px = fmaxf(px, sc[reg]);
    px = fmaxf(px, __shfl_xor(px, 32));

    // ---- defer-max rescale (T13, THR=8) ----
    if (!__all(px - m <= 8.f)) {
      const float mn = fmaxf(m, px);
      const float alpha = __expf(m - mn);  // wipes masked-prefix garbage (alpha=0)
      m = mn;
      l *= alpha;
#pragma unroll
      for (int reg = 0; reg < 16; ++reg) { o0[reg] *= alpha; o1[reg] *= alpha; }
    }

    // ---- p = exp(s - m), row sum ----
    float rs = 0.f;
#pragma unroll
    for (int reg = 0; reg < 16; ++reg) {
      sc[reg] = __expf(sc[reg] - m);
      rs += sc[reg];
    }
    rs += __shfl_xor(rs, 32);
    l += rs;

    // ---- pack P -> A-frags: 8 cvt_pk + 4 permlane32_swap (T12) ----
    unsigned w0 = cvtpk(sc[0], sc[1]),   w2p = cvtpk(sc[4], sc[5]);
    unsigned w1 = cvtpk(sc[2], sc[3]),   w3p = cvtpk(sc[6], sc[7]);
    unsigned u0 = cvtpk(sc[8], sc[9]),   u2p = cvtpk(sc[12], sc[13]);
    unsigned u1 = cvtpk(sc[10], sc[11]), u3p = cvtpk(sc[14], sc[15]);
    SWAP32(w0, w2p);
    SWAP32(w1, w3p);
    SWAP32(u0, u2p);
    SWAP32(u1, u3p);
    union { unsigned u[4]; bf16x8 v; } pu0, pu1;
    pu0.u[0] = w0; pu0.u[1] = w1; pu0.u[2] = w2p; pu0.u[3] = w3p;
    pu1.u[0] = u0; pu1.u[1] = u1; pu1.u[2] = u2p; pu1.u[3] = u3p;

    // ---- PV: O[q][dk] += P·V ----
    __builtin_amdgcn_s_setprio(1);
    o0 = __builtin_amdgcn_mfma_f32_32x32x16_bf16(pu0.v, vf[0][0], o0, 0, 0, 0);
    o0 = __builtin_amdgcn_mfma_f32_32x32x16_bf16(pu1.v, vf[1][0], o0, 0, 0, 0);
    o1 = __builtin_amdgcn_mfma_f32_32x32x16_bf16(pu0.v, vf[0][1], o1, 0, 0, 0);
    o1 = __builtin_amdgcn_mfma_f32_32x32x16_bf16(pu1.v, vf[1][1], o1, 0, 0, 0);
    __builtin_amdgcn_s_setprio(0);

#pragma unroll
    for (int i = 0; i < 4; ++i) kf[i] = kn[i];
    mw = mwn;
  }

  // ---- 4-way split-K merge ----
  if (lane < 32) {
    mlds[kh][ql] = m;
    llds[kh][ql] = l;
  }
  if (kh < 3) {
#pragma unroll
    for (int reg = 0; reg < 16; ++reg) {
      olds[kh][0][reg][lane] = o0[reg];
      olds[kh][1][reg][lane] = o1[reg];
    }
  }
  __syncthreads();
  if (kh == 3) {
#pragma unroll
    for (int reg = 0; reg < 16; ++reg) {
      const int crow = (reg & 3) + 8 * (reg >> 2) + 4 * hi;
      const float m0 = mlds[0][crow], m1 = mlds[1][crow];
      const float m2 = mlds[2][crow], m3 = mlds[3][crow];
      const float ms = fmaxf(fmaxf(m0, m1), fmaxf(m2, m3));
      const float f0 = __expf(m0 - ms), f1 = __expf(m1 - ms);
      const float f2 = __expf(m2 - ms), f3 = __expf(m3 - ms);
      const float ls = llds[0][crow] * f0 + llds[1][crow] * f1 +
                       llds[2][crow] * f2 + llds[3][crow] * f3;
      const float inv = (ms == NEG_BIG) ? 0.f : 1.f / ls;  // fully-masked -> 0
      const float v0 = (olds[0][0][reg][lane] * f0 + olds[1][0][reg][lane] * f1 +
                        olds[2][0][reg][lane] * f2 + o0[reg] * f3) * inv;
      const float v1 = (olds[0][1][reg][lane] * f0 + olds[1][1][reg][lane] * f1 +
                        olds[2][1][reg][lane] * f2 + o1[reg] * f3) * inv;
      const int q = qblk * 32 + crow;
      unsigned short* cp = &ctx[((size_t)(b * S_ + q)) * D_ + h * DK_];
      cp[ql] = f2bf(v0);
      cp[32 + ql] = f2bf(v1);
    }
  }
}

// ---------------------------------------------------------------------------
// Launch
// ---------------------------------------------------------------------------
extern "C" void kernel_launch(void* const* d_in, const int* in_sizes, int n_in,
                              void* d_out, int out_size, void* d_ws,
                              size_t ws_size, hipStream_t stream) {
  const float* query = (const float*)d_in[0];
  const float* key   = (const float*)d_in[1];
  const float* value = (const float*)d_in[2];
  const int*   mask  = (const int*)d_in[3];
  const float* Wq = (const float*)d_in[4];
  const float* bq = (const float*)d_in[5];
  const float* Wk = (const float*)d_in[6];
  const float* bk = (const float*)d_in[7];
  const float* Wv = (const float*)d_in[8];
  const float* bv = (const float*)d_in[9];
  const float* Wo = (const float*)d_in[10];
  const float* bo = (const float*)d_in[11];
  float* out = (float*)d_out;

  const size_t nElem = (size_t)B_ * S_ * D_;  // 4,194,304
  const size_t wElem = (size_t)D_ * D_;       // 1,048,576
  unsigned short* ws = (unsigned short*)d_ws;
  unsigned short* qb   = ws;
  unsigned short* kb   = qb + nElem;
  unsigned short* vb   = kb + nElem;
  unsigned short* wtq  = vb + nElem;
  unsigned short* wtk  = wtq + wElem;
  unsigned short* wtv  = wtk + wElem;
  unsigned short* wto  = wtv + wElem;
  unsigned short* Qh   = wto + wElem;
  unsigned short* Kh   = Qh + nElem;
  unsigned short* VT   = Kh + nElem;
  unsigned short* ctxb = VT + nElem;
  unsigned* mbits = (unsigned*)(ctxb + nElem);

  // 1) pack mask
  {
    const int nwords = B_ * S_ * S_ / 32;
    pack_mask_kernel<<<(nwords + 255) / 256, 256, 0, stream>>>(mask, mbits, nwords);
  }
  // 2) convert activations to bf16 (fused q/k/v)
  {
    const int n8 = (int)(nElem / 8);
    dim3 grid((n8 + 255) / 256, 3);
    cvt_f32_bf16_kernel<<<grid, 256, 0, stream>>>(query, key, value, qb, kb, vb, n8);
  }
  // 3) transpose+convert weights (fused x4)
  {
    dim3 grid(32, 32, 4);
    transpose_w_kernel<<<grid, 256, 0, stream>>>(Wq, Wk, Wv, Wo, wtq, wtk, wtv, wto);
  }
  // 4) QKV projections (fused, z-select)
  {
    dim3 grid(64, 16, 3);
    qkv_gemm_kernel<<<grid, 256, 0, stream>>>(qb, kb, vb, wtq, wtk, wtv,
                                              bq, bk, bv, Qh, Kh, VT);
  }
  // 5) attention (split-K x4, 2048 blocks)
  attn_mfma_kernel<<<2048, 256, 0, stream>>>(Qh, Kh, VT, mbits, ctxb);
  // 6) output projection
  {
    dim3 grid(64, 16);
    out_gemm_kernel<<<grid, 256, 0, stream>>>(ctxb, wto, bo, out);
  }
}

// Round 7
// 352.099 us; speedup vs baseline: 4.7543x; 1.0237x over previous
//
#include <hip/hip_runtime.h>
#include <hip/hip_bf16.h>
#include <cmath>
#include <cstdint>
#include <cstddef>

#define B_  2
#define S_  2048
#define D_  1024
#define H_  16
#define DK_ 64
#define NEG_BIG (-1e30f)
// 0.125 * log2(e): folded into Q projection; softmax runs in exp2 domain.
#define QSCALE 0.1803368801111204f

typedef __attribute__((ext_vector_type(8))) short bf16x8;
typedef __attribute__((ext_vector_type(4))) float f32x4;
typedef __attribute__((ext_vector_type(16))) float f32x16;

static __device__ __forceinline__ unsigned short f2bf(float f) {
  __hip_bfloat16 h = __float2bfloat16(f);
  return *reinterpret_cast<unsigned short*>(&h);
}

static __device__ __forceinline__ unsigned cvtpk(float lo, float hi) {
  unsigned d;
  asm("v_cvt_pk_bf16_f32 %0, %1, %2" : "=v"(d) : "v"(lo), "v"(hi));
  return d;
}
#define SWAP32(a, b) asm("v_permlane32_swap_b32 %0, %1" : "+v"(a), "+v"(b))

typedef __attribute__((address_space(3))) unsigned int lds_u32;
typedef __attribute__((address_space(1))) const unsigned int glb_u32;

// ---------------------------------------------------------------------------
// pack mask via ballot: 1 coalesced int per lane; wave -> 2 bitmask words.
// bit=1 means MASKED (-> -inf).
// ---------------------------------------------------------------------------
__global__ void pack_mask_kernel(const int* __restrict__ mask,
                                 unsigned* __restrict__ bits) {
  const int t = blockIdx.x * 256 + threadIdx.x;
  const unsigned long long ball = __ballot(mask[t] != 0);
  const int lane = threadIdx.x & 63;
  if ((lane & 31) == 0)
    bits[t >> 5] = (lane == 0) ? (unsigned)ball : (unsigned)(ball >> 32);
}

// ---------------------------------------------------------------------------
// fp32 -> bf16 convert, fused over q/k/v via blockIdx.y (8 elems/thread)
// ---------------------------------------------------------------------------
__global__ void cvt_f32_bf16_kernel(const float* __restrict__ q,
                                    const float* __restrict__ k,
                                    const float* __restrict__ v,
                                    unsigned short* __restrict__ qo,
                                    unsigned short* __restrict__ ko,
                                    unsigned short* __restrict__ vo, int n8) {
  int i = blockIdx.x * blockDim.x + threadIdx.x;
  if (i >= n8) return;
  const float* in = (blockIdx.y == 0) ? q : (blockIdx.y == 1) ? k : v;
  unsigned short* out = (blockIdx.y == 0) ? qo : (blockIdx.y == 1) ? ko : vo;
  const float4* p = reinterpret_cast<const float4*>(in) + (size_t)i * 2;
  float4 a = p[0], b = p[1];
  ushort4 o0 = {f2bf(a.x), f2bf(a.y), f2bf(a.z), f2bf(a.w)};
  ushort4 o1 = {f2bf(b.x), f2bf(b.y), f2bf(b.z), f2bf(b.w)};
  ushort4* o = reinterpret_cast<ushort4*>(out) + (size_t)i * 2;
  o[0] = o0;
  o[1] = o1;
}

// ---------------------------------------------------------------------------
// W [K=1024][N=1024] fp32 -> Wt bf16 [N][K], fused over 4 weights (blockIdx.z)
// ---------------------------------------------------------------------------
__global__ __launch_bounds__(256) void transpose_w_kernel(
    const float* __restrict__ w0, const float* __restrict__ w1,
    const float* __restrict__ w2, const float* __restrict__ w3,
    unsigned short* __restrict__ t0, unsigned short* __restrict__ t1,
    unsigned short* __restrict__ t2, unsigned short* __restrict__ t3) {
  __shared__ unsigned short tile[32][33];
  const int z = blockIdx.z;
  const float* W = (z == 0) ? w0 : (z == 1) ? w1 : (z == 2) ? w2 : w3;
  unsigned short* Wt = (z == 0) ? t0 : (z == 1) ? t1 : (z == 2) ? t2 : t3;
  const int r0 = blockIdx.y * 32, c0 = blockIdx.x * 32;
  const int t = threadIdx.x;
  {
    const int r = t >> 3, c4 = (t & 7) * 4;
    float4 v = *reinterpret_cast<const float4*>(&W[(size_t)(r0 + r) * D_ + c0 + c4]);
    tile[c4 + 0][r] = f2bf(v.x);
    tile[c4 + 1][r] = f2bf(v.y);
    tile[c4 + 2][r] = f2bf(v.z);
    tile[c4 + 3][r] = f2bf(v.w);
  }
  __syncthreads();
  {
    const int n = t >> 3, k4 = (t & 7) * 4;
    ushort4 o = {tile[n][k4 + 0], tile[n][k4 + 1], tile[n][k4 + 2], tile[n][k4 + 3]};
    *reinterpret_cast<ushort4*>(&Wt[(size_t)(c0 + n) * D_ + r0 + k4]) = o;
  }
}

// ---------------------------------------------------------------------------
// 128x128-tile bf16 MFMA GEMM (m97 structure): BK=32, 256 thr (4 waves, 2x2
// of 64x64), 4x4 16x16x32 frags per wave, global_load_lds staging.
// Fused QKV: blockIdx.z selects {q,k,v}. Q scaled by QSCALE (exp2 domain).
// ---------------------------------------------------------------------------
__global__ __launch_bounds__(256) void qkv_gemm_kernel(
    const unsigned short* __restrict__ qb, const unsigned short* __restrict__ kb,
    const unsigned short* __restrict__ vb, const unsigned short* __restrict__ wtq,
    const unsigned short* __restrict__ wtk, const unsigned short* __restrict__ wtv,
    const float* __restrict__ bq, const float* __restrict__ bk,
    const float* __restrict__ bv, unsigned short* __restrict__ Qh,
    unsigned short* __restrict__ Kh, unsigned short* __restrict__ VT) {
  constexpr int K = D_;
  __shared__ __attribute__((aligned(16))) unsigned short as_[128 * 32];
  __shared__ __attribute__((aligned(16))) unsigned short bs_[128 * 32];
  const int z = blockIdx.z;
  const unsigned short* A = (z == 0) ? qb : (z == 1) ? kb : vb;
  const unsigned short* Wt = (z == 0) ? wtq : (z == 1) ? wtk : wtv;
  const float* bias = (z == 0) ? bq : (z == 1) ? bk : bv;

  const int bm = blockIdx.x * 128, bn = blockIdx.y * 128;
  const int t = threadIdx.x, wv = t >> 6, lane = t & 63;
  const int r = lane & 15, g = lane >> 4;
  const int wr = (wv >> 1) * 64, wc = (wv & 1) * 64;
  const int srow = 16 * wv + (lane >> 2);  // staging row within 64-row chunk
  const int scol = (lane & 3) * 8;

  f32x4 acc[4][4] = {};

  for (int k0 = 0; k0 < K; k0 += 32) {
    __syncthreads();
    __builtin_amdgcn_global_load_lds(
        (glb_u32*)&A[(size_t)(bm + srow) * K + k0 + scol],
        (lds_u32*)(as_ + wv * 512), 16, 0, 0);
    __builtin_amdgcn_global_load_lds(
        (glb_u32*)&A[(size_t)(bm + 64 + srow) * K + k0 + scol],
        (lds_u32*)(as_ + wv * 512 + 2048), 16, 0, 0);
    __builtin_amdgcn_global_load_lds(
        (glb_u32*)&Wt[(size_t)(bn + srow) * K + k0 + scol],
        (lds_u32*)(bs_ + wv * 512), 16, 0, 0);
    __builtin_amdgcn_global_load_lds(
        (glb_u32*)&Wt[(size_t)(bn + 64 + srow) * K + k0 + scol],
        (lds_u32*)(bs_ + wv * 512 + 2048), 16, 0, 0);
    __syncthreads();

    bf16x8 a[4], bfr[4];
#pragma unroll
    for (int mf = 0; mf < 4; ++mf)
      a[mf] = *reinterpret_cast<const bf16x8*>(&as_[(wr + 16 * mf + r) * 32 + 8 * g]);
#pragma unroll
    for (int nf = 0; nf < 4; ++nf)
      bfr[nf] = *reinterpret_cast<const bf16x8*>(&bs_[(wc + 16 * nf + r) * 32 + 8 * g]);
#pragma unroll
    for (int mf = 0; mf < 4; ++mf)
#pragma unroll
      for (int nf = 0; nf < 4; ++nf)
        acc[mf][nf] = __builtin_amdgcn_mfma_f32_16x16x32_bf16(a[mf], bfr[nf],
                                                              acc[mf][nf], 0, 0, 0);
  }

#pragma unroll
  for (int mf = 0; mf < 4; ++mf)
#pragma unroll
    for (int nf = 0; nf < 4; ++nf)
#pragma unroll
      for (int reg = 0; reg < 4; ++reg) {
        const int row = bm + wr + 16 * mf + 4 * g + reg;
        const int col = bn + wc + 16 * nf + r;
        const float v = acc[mf][nf][reg] + bias[col];
        const int bb = row >> 11, s = row & (S_ - 1);
        const int h = col >> 6, dk = col & (DK_ - 1);
        if (z == 0)
          Qh[(((size_t)(bb * H_ + h)) * S_ + s) * DK_ + dk] = f2bf(v * QSCALE);
        else if (z == 1)
          Kh[(((size_t)(bb * H_ + h)) * S_ + s) * DK_ + dk] = f2bf(v);
        else
          VT[(((size_t)(bb * H_ + h)) * DK_ + dk) * S_ + s] = f2bf(v);
      }
}

// ---------------------------------------------------------------------------
// Output projection, 128x128 tile: ctx bf16 [B,S,D] @ Wo^T + bo -> fp32 out.
// ---------------------------------------------------------------------------
__global__ __launch_bounds__(256) void out_gemm_kernel(
    const unsigned short* __restrict__ A, const unsigned short* __restrict__ Wt,
    const float* __restrict__ bias, float* __restrict__ Cout) {
  constexpr int K = D_;
  __shared__ __attribute__((aligned(16))) unsigned short as_[128 * 32];
  __shared__ __attribute__((aligned(16))) unsigned short bs_[128 * 32];
  const int bm = blockIdx.x * 128, bn = blockIdx.y * 128;
  const int t = threadIdx.x, wv = t >> 6, lane = t & 63;
  const int r = lane & 15, g = lane >> 4;
  const int wr = (wv >> 1) * 64, wc = (wv & 1) * 64;
  const int srow = 16 * wv + (lane >> 2);
  const int scol = (lane & 3) * 8;

  f32x4 acc[4][4] = {};

  for (int k0 = 0; k0 < K; k0 += 32) {
    __syncthreads();
    __builtin_amdgcn_global_load_lds(
        (glb_u32*)&A[(size_t)(bm + srow) * K + k0 + scol],
        (lds_u32*)(as_ + wv * 512), 16, 0, 0);
    __builtin_amdgcn_global_load_lds(
        (glb_u32*)&A[(size_t)(bm + 64 + srow) * K + k0 + scol],
        (lds_u32*)(as_ + wv * 512 + 2048), 16, 0, 0);
    __builtin_amdgcn_global_load_lds(
        (glb_u32*)&Wt[(size_t)(bn + srow) * K + k0 + scol],
        (lds_u32*)(bs_ + wv * 512), 16, 0, 0);
    __builtin_amdgcn_global_load_lds(
        (glb_u32*)&Wt[(size_t)(bn + 64 + srow) * K + k0 + scol],
        (lds_u32*)(bs_ + wv * 512 + 2048), 16, 0, 0);
    __syncthreads();

    bf16x8 a[4], bfr[4];
#pragma unroll
    for (int mf = 0; mf < 4; ++mf)
      a[mf] = *reinterpret_cast<const bf16x8*>(&as_[(wr + 16 * mf + r) * 32 + 8 * g]);
#pragma unroll
    for (int nf = 0; nf < 4; ++nf)
      bfr[nf] = *reinterpret_cast<const bf16x8*>(&bs_[(wc + 16 * nf + r) * 32 + 8 * g]);
#pragma unroll
    for (int mf = 0; mf < 4; ++mf)
#pragma unroll
      for (int nf = 0; nf < 4; ++nf)
        acc[mf][nf] = __builtin_amdgcn_mfma_f32_16x16x32_bf16(a[mf], bfr[nf],
                                                              acc[mf][nf], 0, 0, 0);
  }

#pragma unroll
  for (int mf = 0; mf < 4; ++mf)
#pragma unroll
    for (int nf = 0; nf < 4; ++nf)
#pragma unroll
      for (int reg = 0; reg < 4; ++reg) {
        const int row = bm + wr + 16 * mf + 4 * g + reg;
        const int col = bn + wc + 16 * nf + r;
        Cout[(size_t)row * D_ + col] = acc[mf][nf][reg] + bias[col];
      }
}

// ---------------------------------------------------------------------------
// MFMA flash attention: 32x32x16 swapped-QK^T, split-K(4), defer-max, T12
// pack, exp2-domain softmax, pointer-increment addressing, unroll x2 with
// alternating K-frag sets, V/mask loads issued at body top (latency hidden
// under QK^T+softmax), K prefetched one tile ahead.
// ---------------------------------------------------------------------------
#define ATTN_BODY(KF, KN, PRE)                                                 \
  do {                                                                         \
    const unsigned mw = *mp;                                                   \
    ++mp;                                                                      \
    const bf16x8 vf00 = *(const bf16x8*)(vb0);                                 \
    const bf16x8 vf01 = *(const bf16x8*)(vb0 + 16);                            \
    const bf16x8 vf10 = *(const bf16x8*)(vb1);                                 \
    const bf16x8 vf11 = *(const bf16x8*)(vb1 + 16);                            \
    vb0 += 32;                                                                 \
    vb1 += 32;                                                                 \
    if (PRE) {                                                                 \
      KN[0] = *(const bf16x8*)(kbase);                                         \
      KN[1] = *(const bf16x8*)(kbase + 16);                                    \
      KN[2] = *(const bf16x8*)(kbase + 32);                                    \
      KN[3] = *(const bf16x8*)(kbase + 48);                                    \
      kbase += 2048;                                                           \
    }                                                                          \
    f32x16 sc = {};                                                            \
    sc = __builtin_amdgcn_mfma_f32_32x32x16_bf16(KF[0], qf[0], sc, 0, 0, 0);   \
    sc = __builtin_amdgcn_mfma_f32_32x32x16_bf16(KF[1], qf[1], sc, 0, 0, 0);   \
    sc = __builtin_amdgcn_mfma_f32_32x32x16_bf16(KF[2], qf[2], sc, 0, 0, 0);   \
    sc = __builtin_amdgcn_mfma_f32_32x32x16_bf16(KF[3], qf[3], sc, 0, 0, 0);   \
    const unsigned msh = mw >> (4 * hi);                                       \
    _Pragma("unroll") for (int reg = 0; reg < 16; ++reg) {                     \
      const int creg = (reg & 3) + 8 * (reg >> 2);                             \
      if ((msh >> creg) & 1u) sc[reg] = NEG_BIG;                               \
    }                                                                          \
    float px;                                                                  \
    {                                                                          \
      const float t0 = fmaxf(fmaxf(sc[0], sc[1]), sc[2]);                      \
      const float t1 = fmaxf(fmaxf(sc[3], sc[4]), sc[5]);                      \
      const float t2 = fmaxf(fmaxf(sc[6], sc[7]), sc[8]);                      \
      const float t3 = fmaxf(fmaxf(sc[9], sc[10]), sc[11]);                    \
      const float t4 = fmaxf(fmaxf(sc[12], sc[13]), sc[14]);                   \
      const float u0 = fmaxf(fmaxf(t0, t1), t2);                               \
      const float u1 = fmaxf(fmaxf(t3, t4), sc[15]);                           \
      px = fmaxf(u0, u1);                                                      \
    }                                                                          \
    px = fmaxf(px, __shfl_xor(px, 32));                                        \
    if (!__all(px - m <= 11.f)) {                                              \
      const float mn = fmaxf(m, px);                                           \
      const float al = exp2f(m - mn);                                          \
      m = mn;                                                                  \
      l *= al;                                                                 \
      _Pragma("unroll") for (int reg = 0; reg < 16; ++reg) {                   \
        o0[reg] *= al;                                                         \
        o1[reg] *= al;                                                         \
      }                                                                        \
    }                                                                          \
    _Pragma("unroll") for (int reg = 0; reg < 16; ++reg)                       \
        sc[reg] = exp2f(sc[reg] - m);                                          \
    {                                                                          \
      const float s0 = (sc[0] + sc[1]) + (sc[2] + sc[3]);                      \
      const float s1 = (sc[4] + sc[5]) + (sc[6] + sc[7]);                      \
      const float s2 = (sc[8] + sc[9]) + (sc[10] + sc[11]);                    \
      const float s3 = (sc[12] + sc[13]) + (sc[14] + sc[15]);                  \
      float rs = (s0 + s1) + (s2 + s3);                                        \
      rs += __shfl_xor(rs, 32);                                                \
      l += rs;                                                                 \
    }                                                                          \
    unsigned w0 = cvtpk(sc[0], sc[1]), w2p = cvtpk(sc[4], sc[5]);              \
    unsigned w1 = cvtpk(sc[2], sc[3]), w3p = cvtpk(sc[6], sc[7]);              \
    unsigned u0 = cvtpk(sc[8], sc[9]), u2p = cvtpk(sc[12], sc[13]);            \
    unsigned u1 = cvtpk(sc[10], sc[11]), u3p = cvtpk(sc[14], sc[15]);          \
    SWAP32(w0, w2p);                                                           \
    SWAP32(w1, w3p);                                                           \
    SWAP32(u0, u2p);                                                           \
    SWAP32(u1, u3p);                                                           \
    union { unsigned u[4]; bf16x8 v; } pu0, pu1;                               \
    pu0.u[0] = w0; pu0.u[1] = w1; pu0.u[2] = w2p; pu0.u[3] = w3p;              \
    pu1.u[0] = u0; pu1.u[1] = u1; pu1.u[2] = u2p; pu1.u[3] = u3p;              \
    o0 = __builtin_amdgcn_mfma_f32_32x32x16_bf16(pu0.v, vf00, o0, 0, 0, 0);    \
    o0 = __builtin_amdgcn_mfma_f32_32x32x16_bf16(pu1.v, vf01, o0, 0, 0, 0);    \
    o1 = __builtin_amdgcn_mfma_f32_32x32x16_bf16(pu0.v, vf10, o1, 0, 0, 0);    \
    o1 = __builtin_amdgcn_mfma_f32_32x32x16_bf16(pu1.v, vf11, o1, 0, 0, 0);    \
  } while (0)

__global__ __launch_bounds__(256) void attn_mfma_kernel(
    const unsigned short* __restrict__ Qh, const unsigned short* __restrict__ Kh,
    const unsigned short* __restrict__ VT, const unsigned* __restrict__ mbits,
    unsigned short* __restrict__ ctx) {
  __shared__ float mlds[4][32];
  __shared__ float llds[4][32];
  __shared__ float olds[3][2][16][64];

  const int flat = blockIdx.x;
  const int bh = (flat & 7) * 4 + ((flat >> 3) & 3);  // 4 heads per XCD
  const int qblk = flat >> 5;                          // 0..63
  const int b = bh >> 4, h = bh & 15;
  const int kh = threadIdx.x >> 6, lane = threadIdx.x & 63;
  const int ql = lane & 31, hi = lane >> 5;
  const int qrow = qblk * 32 + ql;

  const unsigned short* Qrow = &Qh[((size_t)bh * S_ + qrow) * DK_];
  bf16x8 qf[4];
#pragma unroll
  for (int i = 0; i < 4; ++i)
    qf[i] = *(const bf16x8*)&Qrow[16 * i + 8 * hi];

  const unsigned short* Khead = &Kh[(size_t)bh * S_ * DK_];
  const unsigned short* Vhead = &VT[(size_t)bh * DK_ * S_];

  f32x16 o0 = {}, o1 = {};
  float m = NEG_BIG, l = 0.f;

  const int tbeg = kh * 16;  // 16 tiles of 32 keys per wave
  const unsigned short* kbase = Khead + ((size_t)(tbeg * 32 + ql)) * DK_ + 8 * hi;
  const unsigned short* vb0 = Vhead + (size_t)ql * S_ + tbeg * 32 + 8 * hi;
  const unsigned short* vb1 = vb0 + (size_t)32 * S_;
  const unsigned* mp = &mbits[((size_t)b * S_ + qrow) * (S_ / 32) + tbeg];

  bf16x8 kfA[4], kfB[4];
  kfA[0] = *(const bf16x8*)(kbase);
  kfA[1] = *(const bf16x8*)(kbase + 16);
  kfA[2] = *(const bf16x8*)(kbase + 32);
  kfA[3] = *(const bf16x8*)(kbase + 48);
  kbase += 2048;

#pragma unroll 1
  for (int it = 0; it < 7; ++it) {
    ATTN_BODY(kfA, kfB, 1);
    ATTN_BODY(kfB, kfA, 1);
  }
  ATTN_BODY(kfA, kfB, 1);
  ATTN_BODY(kfB, kfA, 0);

  // ---- 4-way split-K merge ----
  if (lane < 32) {
    mlds[kh][ql] = m;
    llds[kh][ql] = l;
  }
  if (kh < 3) {
#pragma unroll
    for (int reg = 0; reg < 16; ++reg) {
      olds[kh][0][reg][lane] = o0[reg];
      olds[kh][1][reg][lane] = o1[reg];
    }
  }
  __syncthreads();
  if (kh == 3) {
#pragma unroll
    for (int reg = 0; reg < 16; ++reg) {
      const int crow = (reg & 3) + 8 * (reg >> 2) + 4 * hi;
      const float m0 = mlds[0][crow], m1 = mlds[1][crow];
      const float m2 = mlds[2][crow], m3 = mlds[3][crow];
      const float ms = fmaxf(fmaxf(m0, m1), fmaxf(m2, m3));
      const float f0 = exp2f(m0 - ms), f1 = exp2f(m1 - ms);
      const float f2 = exp2f(m2 - ms), f3 = exp2f(m3 - ms);
      const float ls = llds[0][crow] * f0 + llds[1][crow] * f1 +
                       llds[2][crow] * f2 + llds[3][crow] * f3;
      const float inv = (ms == NEG_BIG) ? 0.f : 1.f / ls;  // fully-masked -> 0
      const float v0 = (olds[0][0][reg][lane] * f0 + olds[1][0][reg][lane] * f1 +
                        olds[2][0][reg][lane] * f2 + o0[reg] * f3) * inv;
      const float v1 = (olds[0][1][reg][lane] * f0 + olds[1][1][reg][lane] * f1 +
                        olds[2][1][reg][lane] * f2 + o1[reg] * f3) * inv;
      const int q = qblk * 32 + crow;
      unsigned short* cp = &ctx[((size_t)(b * S_ + q)) * D_ + h * DK_];
      cp[ql] = f2bf(v0);
      cp[32 + ql] = f2bf(v1);
    }
  }
}

// ---------------------------------------------------------------------------
// Launch
// ---------------------------------------------------------------------------
extern "C" void kernel_launch(void* const* d_in, const int* in_sizes, int n_in,
                              void* d_out, int out_size, void* d_ws,
                              size_t ws_size, hipStream_t stream) {
  const float* query = (const float*)d_in[0];
  const float* key   = (const float*)d_in[1];
  const float* value = (const float*)d_in[2];
  const int*   mask  = (const int*)d_in[3];
  const float* Wq = (const float*)d_in[4];
  const float* bq = (const float*)d_in[5];
  const float* Wk = (const float*)d_in[6];
  const float* bk = (const float*)d_in[7];
  const float* Wv = (const float*)d_in[8];
  const float* bv = (const float*)d_in[9];
  const float* Wo = (const float*)d_in[10];
  const float* bo = (const float*)d_in[11];
  float* out = (float*)d_out;

  const size_t nElem = (size_t)B_ * S_ * D_;  // 4,194,304
  const size_t wElem = (size_t)D_ * D_;       // 1,048,576
  unsigned short* ws = (unsigned short*)d_ws;
  unsigned short* qb   = ws;
  unsigned short* kb   = qb + nElem;
  unsigned short* vb   = kb + nElem;
  unsigned short* wtq  = vb + nElem;
  unsigned short* wtk  = wtq + wElem;
  unsigned short* wtv  = wtk + wElem;
  unsigned short* wto  = wtv + wElem;
  unsigned short* Qh   = wto + wElem;
  unsigned short* Kh   = Qh + nElem;
  unsigned short* VT   = Kh + nElem;
  unsigned short* ctxb = VT + nElem;
  unsigned* mbits = (unsigned*)(ctxb + nElem);

  // 1) pack mask (ballot, fully coalesced)
  pack_mask_kernel<<<(B_ * S_ * S_) / 256, 256, 0, stream>>>(mask, mbits);
  // 2) convert activations to bf16 (fused q/k/v)
  {
    const int n8 = (int)(nElem / 8);
    dim3 grid((n8 + 255) / 256, 3);
    cvt_f32_bf16_kernel<<<grid, 256, 0, stream>>>(query, key, value, qb, kb, vb, n8);
  }
  // 3) transpose+convert weights (fused x4)
  {
    dim3 grid(32, 32, 4);
    transpose_w_kernel<<<grid, 256, 0, stream>>>(Wq, Wk, Wv, Wo, wtq, wtk, wtv, wto);
  }
  // 4) QKV projections (fused, 128x128 tiles)
  {
    dim3 grid(32, 8, 3);
    qkv_gemm_kernel<<<grid, 256, 0, stream>>>(qb, kb, vb, wtq, wtk, wtv,
                                              bq, bk, bv, Qh, Kh, VT);
  }
  // 5) attention (split-K x4, 2048 blocks)
  attn_mfma_kernel<<<2048, 256, 0, stream>>>(Qh, Kh, VT, mbits, ctxb);
  // 6) output projection (128x128 tiles)
  {
    dim3 grid(32, 8);
    out_gemm_kernel<<<grid, 256, 0, stream>>>(ctxb, wto, bo, out);
  }
}